// Round 1
// baseline (1073.946 us; speedup 1.0000x reference)
//
#include <hip/hip_runtime.h>
#include <hip/hip_bf16.h>
#include <math.h>

// ---------------------------------------------------------------------------
// GCN part-seg pipeline, fp32 correctness-first implementation.
// x[50000,3] --MLP(3->32->64->128, relu)--> h3
// 3x GCNConv (CSR-based segment-sum, no atomics) -> softmax(50)
// ---------------------------------------------------------------------------

#define WAVE 64

// ---------------- degree / CSR build ----------------

__global__ void hist_kernel(const int* __restrict__ dst, int* __restrict__ counts, int e) {
    int g = blockIdx.x * blockDim.x + threadIdx.x;
    if (g < e) atomicAdd(&counts[dst[g]], 1);
}

__global__ void dinv_kernel(const int* __restrict__ counts, float* __restrict__ dinv, int n) {
    int g = blockIdx.x * blockDim.x + threadIdx.x;
    if (g < n) dinv[g] = rsqrtf((float)counts[g] + 1.0f);
}

// single-block exclusive scan of counts -> offsets (and cursor copy)
__global__ void scan_kernel(const int* __restrict__ counts, int* __restrict__ offsets,
                            int* __restrict__ cursor, int n) {
    __shared__ int buf[1024];
    __shared__ int carry;
    int tid = threadIdx.x;
    if (tid == 0) carry = 0;
    __syncthreads();
    for (int base = 0; base < n; base += 1024) {
        int i = base + tid;
        int v = (i < n) ? counts[i] : 0;
        buf[tid] = v;
        __syncthreads();
        for (int off = 1; off < 1024; off <<= 1) {
            int t = (tid >= off) ? buf[tid - off] : 0;
            __syncthreads();
            buf[tid] += t;
            __syncthreads();
        }
        int excl = carry + buf[tid] - v;
        if (i < n) { offsets[i] = excl; cursor[i] = excl; }
        __syncthreads();
        if (tid == 0) carry += buf[1023];
        __syncthreads();
    }
    if (tid == 0) offsets[n] = carry;
}

__global__ void fill_kernel(const int* __restrict__ src, const int* __restrict__ dst,
                            const float* __restrict__ dinv, int* __restrict__ cursor,
                            int* __restrict__ ssrc, float* __restrict__ snorm, int e) {
    int g = blockIdx.x * blockDim.x + threadIdx.x;
    if (g >= e) return;
    int s = src[g], d = dst[g];
    int pos = atomicAdd(&cursor[d], 1);
    ssrc[pos]  = s;
    snorm[pos] = dinv[s] * dinv[d];
}

// ---------------- MLP layer 1 (K=3) ----------------

__global__ void mlp1_kernel(const float* __restrict__ x, const float* __restrict__ w1,
                            const float* __restrict__ b1, float* __restrict__ h1, int n) {
    int gid = blockIdx.x * blockDim.x + threadIdx.x;
    if (gid >= n * 32) return;
    int node = gid >> 5, j = gid & 31;
    float x0 = x[node * 3 + 0], x1 = x[node * 3 + 1], x2 = x[node * 3 + 2];
    float v = b1[j] + x0 * w1[j] + x1 * w1[32 + j] + x2 * w1[64 + j];
    h1[gid] = fmaxf(v, 0.0f);
}

// ---------------- tiled fp32 GEMM: C[M,N] = A[M,K] @ B[K,N] (+bias, relu) ----
// 64x64 tile, 256 threads, 4x4 micro-tile, KT=16. Requires K % 16 == 0.

template<bool BIAS, bool RELU>
__global__ __launch_bounds__(256) void gemm_kernel(
        const float* __restrict__ A, const float* __restrict__ B,
        const float* __restrict__ bias, float* __restrict__ C,
        int M, int N, int K) {
    __shared__ float As[16][68];
    __shared__ float Bs[16][68];
    const int tid = threadIdx.x;
    const int tx = tid & 15, ty = tid >> 4;
    const int bm = blockIdx.y * 64, bn = blockIdx.x * 64;
    const bool nvec = ((N & 63) == 0);   // vectorized B path when N % 64 == 0

    float acc[4][4];
#pragma unroll
    for (int i = 0; i < 4; i++)
#pragma unroll
        for (int j = 0; j < 4; j++) acc[i][j] = 0.0f;

    for (int k0 = 0; k0 < K; k0 += 16) {
        // A tile: 64 rows x 16 k, one float4 per thread along K
        {
            int m  = tid >> 2;             // 0..63
            int kq = (tid & 3) * 4;        // 0,4,8,12
            int gm = bm + m;
            float4 av = make_float4(0.f, 0.f, 0.f, 0.f);
            if (gm < M) av = *(const float4*)&A[(size_t)gm * K + k0 + kq];
            As[kq + 0][m] = av.x; As[kq + 1][m] = av.y;
            As[kq + 2][m] = av.z; As[kq + 3][m] = av.w;
        }
        // B tile: 16 k x 64 n
        if (nvec) {
            int kb = tid >> 4;             // 0..15
            int nb = (tid & 15) * 4;       // 0..60
            float4 bv = *(const float4*)&B[(size_t)(k0 + kb) * N + bn + nb];
            *(float4*)&Bs[kb][nb] = bv;
        } else {
#pragma unroll
            for (int i = 0; i < 4; i++) {
                int idx = i * 256 + tid;
                int kb = idx >> 6, nb = idx & 63;
                int gn = bn + nb;
                Bs[kb][nb] = (gn < N) ? B[(size_t)(k0 + kb) * N + gn] : 0.0f;
            }
        }
        __syncthreads();

#pragma unroll
        for (int kk = 0; kk < 16; kk++) {
            float4 a4 = *(const float4*)&As[kk][ty * 4];
            float4 b4 = *(const float4*)&Bs[kk][tx * 4];
            float av[4] = {a4.x, a4.y, a4.z, a4.w};
            float bv[4] = {b4.x, b4.y, b4.z, b4.w};
#pragma unroll
            for (int i = 0; i < 4; i++)
#pragma unroll
                for (int j = 0; j < 4; j++)
                    acc[i][j] = fmaf(av[i], bv[j], acc[i][j]);
        }
        __syncthreads();
    }

#pragma unroll
    for (int i = 0; i < 4; i++) {
        int gm = bm + ty * 4 + i;
        if (gm >= M) continue;
#pragma unroll
        for (int j = 0; j < 4; j++) {
            int gn = bn + tx * 4 + j;
            if (gn >= N) continue;
            float v = acc[i][j];
            if (BIAS) v += bias[gn];
            if (RELU) v = fmaxf(v, 0.0f);
            C[(size_t)gm * N + gn] = v;
        }
    }
}

// ---------------- GCN aggregation: one block per dst node -------------------
// out[d] = sum_{e in CSR[d]} hw[src_e]*norm_e  +  hw[d]*dinv[d]^2  +  bias

template<int F, int TPB>
__global__ __launch_bounds__(TPB) void agg_kernel(
        const float* __restrict__ hw, const int* __restrict__ offsets,
        const int* __restrict__ ssrc, const float* __restrict__ snorm,
        const float* __restrict__ dinv, const float* __restrict__ bias,
        float* __restrict__ out, int n, int relu) {
    int node = blockIdx.x;
    if (node >= n) return;
    constexpr int VPT = (F + TPB - 1) / TPB;
    float acc[VPT];
#pragma unroll
    for (int v = 0; v < VPT; v++) acc[v] = 0.0f;

    int beg = offsets[node], end = offsets[node + 1];
    for (int e = beg; e < end; ++e) {
        int s = ssrc[e];
        float w = snorm[e];
        const float* row = hw + (size_t)s * F;
#pragma unroll
        for (int v = 0; v < VPT; v++) {
            int f = threadIdx.x + v * TPB;
            if ((F % TPB == 0) || f < F) acc[v] += row[f] * w;
        }
    }
    float dv = dinv[node];
    float sw = dv * dv;
    const float* srow = hw + (size_t)node * F;
#pragma unroll
    for (int v = 0; v < VPT; v++) {
        int f = threadIdx.x + v * TPB;
        if ((F % TPB == 0) || f < F) {
            float r = acc[v] + srow[f] * sw + bias[f];
            if (relu) r = fmaxf(r, 0.0f);
            out[(size_t)node * F + f] = r;
        }
    }
}

// ---------------- softmax over 50 features, one wave per node ---------------

__global__ void softmax_kernel(float* __restrict__ out, int n) {
    int node = blockIdx.x * 4 + (threadIdx.x >> 6);
    int lane = threadIdx.x & 63;
    if (node >= n) return;
    float v = (lane < 50) ? out[node * 50 + lane] : -INFINITY;
    float m = v;
#pragma unroll
    for (int off = 32; off > 0; off >>= 1) m = fmaxf(m, __shfl_xor(m, off));
    float e = (lane < 50) ? expf(v - m) : 0.0f;
    float s = e;
#pragma unroll
    for (int off = 32; off > 0; off >>= 1) s += __shfl_xor(s, off);
    if (lane < 50) out[node * 50 + lane] = e / s;
}

// ---------------------------------------------------------------------------

extern "C" void kernel_launch(void* const* d_in, const int* in_sizes, int n_in,
                              void* d_out, int out_size, void* d_ws, size_t ws_size,
                              hipStream_t stream) {
    const float* x    = (const float*)d_in[0];
    const int*   ei   = (const int*)  d_in[1];
    const float* w1   = (const float*)d_in[2];
    const float* b1   = (const float*)d_in[3];
    const float* w2   = (const float*)d_in[4];
    const float* b2   = (const float*)d_in[5];
    const float* w3   = (const float*)d_in[6];
    const float* b3   = (const float*)d_in[7];
    const float* g1w  = (const float*)d_in[8];
    const float* g1b  = (const float*)d_in[9];
    const float* g2w  = (const float*)d_in[10];
    const float* g2b  = (const float*)d_in[11];
    const float* g3w  = (const float*)d_in[12];
    const float* g3b  = (const float*)d_in[13];
    float* out = (float*)d_out;

    const int N = in_sizes[0] / 3;      // 50000
    const int E = in_sizes[1] / 2;      // 800000
    const int* src = ei;
    const int* dst = ei + E;

    // workspace arena (256B-aligned slots)
    char* ws = (char*)d_ws;
    size_t off = 0;
    auto alloc = [&](size_t bytes) -> char* {
        char* p = ws + off;
        off = (off + bytes + 255) & ~(size_t)255;
        return p;
    };
    int*   counts  = (int*)  alloc((size_t)N * 4);
    int*   offsets = (int*)  alloc((size_t)(N + 1) * 4);
    int*   cursor  = (int*)  alloc((size_t)N * 4);
    float* dinv    = (float*)alloc((size_t)N * 4);
    int*   ssrc    = (int*)  alloc((size_t)E * 4);
    float* snorm   = (float*)alloc((size_t)E * 4);
    float* slotC   = (float*)alloc((size_t)N * 128 * 4);   // 25.6 MB
    float* slotA   = (float*)alloc((size_t)N * 512 * 4);   // 102.4 MB
    float* slotB   = (float*)alloc((size_t)N * 512 * 4);   // 102.4 MB
    (void)ws_size;

    // ---- degree + CSR ----
    hipMemsetAsync(counts, 0, (size_t)N * 4, stream);
    hist_kernel<<<(E + 255) / 256, 256, 0, stream>>>(dst, counts, E);
    dinv_kernel<<<(N + 255) / 256, 256, 0, stream>>>(counts, dinv, N);
    scan_kernel<<<1, 1024, 0, stream>>>(counts, offsets, cursor, N);
    fill_kernel<<<(E + 255) / 256, 256, 0, stream>>>(src, dst, dinv, cursor, ssrc, snorm, E);

    // ---- MLP ----
    mlp1_kernel<<<((size_t)N * 32 + 255) / 256, 256, 0, stream>>>(x, w1, b1, slotA, N);
    {   // h2 = relu(h1 @ w2 + b2): M=N, K=32, Nf=64
        dim3 grid((64 + 63) / 64, (N + 63) / 64);
        gemm_kernel<true, true><<<grid, 256, 0, stream>>>(slotA, w2, b2, slotB, N, 64, 32);
    }
    {   // h3 = relu(h2 @ w3 + b3): K=64, Nf=128
        dim3 grid((128 + 63) / 64, (N + 63) / 64);
        gemm_kernel<true, true><<<grid, 256, 0, stream>>>(slotB, w3, b3, slotC, N, 128, 64);
    }

    // ---- GCN layer 1: 128 -> 256 ----
    {
        dim3 grid((256 + 63) / 64, (N + 63) / 64);
        gemm_kernel<false, false><<<grid, 256, 0, stream>>>(slotC, g1w, nullptr, slotA, N, 256, 128);
        agg_kernel<256, 256><<<N, 256, 0, stream>>>(slotA, offsets, ssrc, snorm, dinv, g1b, slotB, N, 1);
    }
    // ---- GCN layer 2: 256 -> 512 ----
    {
        dim3 grid((512 + 63) / 64, (N + 63) / 64);
        gemm_kernel<false, false><<<grid, 256, 0, stream>>>(slotB, g2w, nullptr, slotA, N, 512, 256);
        agg_kernel<512, 256><<<N, 256, 0, stream>>>(slotA, offsets, ssrc, snorm, dinv, g2b, slotB, N, 1);
    }
    // ---- GCN layer 3: 512 -> 50 ----
    {
        dim3 grid((50 + 63) / 64, (N + 63) / 64);
        gemm_kernel<false, false><<<grid, 256, 0, stream>>>(slotB, g3w, nullptr, slotC, N, 50, 512);
        agg_kernel<50, 64><<<N, 64, 0, stream>>>(slotC, offsets, ssrc, snorm, dinv, g3b, out, N, 0);
    }

    // ---- softmax ----
    softmax_kernel<<<(N + 3) / 4, 256, 0, stream>>>(out, N);
}

// Round 2
// 832.172 us; speedup vs baseline: 1.2905x; 1.2905x over previous
//
#include <hip/hip_runtime.h>
#include <hip/hip_bf16.h>
#include <math.h>

// ---------------------------------------------------------------------------
// GCN part-seg pipeline, fp32.
// R2: (1) aggregate BEFORE weight matmul in GCN layers 1-2 (AGG(hW)=AGG(h)W)
//     to shrink gather traffic 2x; (2) vectorized thread-per-(node,chunk)
//     aggregation; (3) 128x128-tile 8x8-microtile fp32 GEMM.
// ---------------------------------------------------------------------------

// ---------------- degree / CSR build ----------------

__global__ void hist_kernel(const int* __restrict__ dst, int* __restrict__ counts, int e) {
    int g = blockIdx.x * blockDim.x + threadIdx.x;
    if (g < e) atomicAdd(&counts[dst[g]], 1);
}

__global__ void dinv_kernel(const int* __restrict__ counts, float* __restrict__ dinv, int n) {
    int g = blockIdx.x * blockDim.x + threadIdx.x;
    if (g < n) dinv[g] = rsqrtf((float)counts[g] + 1.0f);
}

// single-block exclusive scan of counts -> offsets (and cursor copy)
__global__ void scan_kernel(const int* __restrict__ counts, int* __restrict__ offsets,
                            int* __restrict__ cursor, int n) {
    __shared__ int buf[1024];
    __shared__ int carry;
    int tid = threadIdx.x;
    if (tid == 0) carry = 0;
    __syncthreads();
    for (int base = 0; base < n; base += 1024) {
        int i = base + tid;
        int v = (i < n) ? counts[i] : 0;
        buf[tid] = v;
        __syncthreads();
        for (int off = 1; off < 1024; off <<= 1) {
            int t = (tid >= off) ? buf[tid - off] : 0;
            __syncthreads();
            buf[tid] += t;
            __syncthreads();
        }
        int excl = carry + buf[tid] - v;
        if (i < n) { offsets[i] = excl; cursor[i] = excl; }
        __syncthreads();
        if (tid == 0) carry += buf[1023];
        __syncthreads();
    }
    if (tid == 0) offsets[n] = carry;
}

__global__ void fill_kernel(const int* __restrict__ src, const int* __restrict__ dst,
                            const float* __restrict__ dinv, int* __restrict__ cursor,
                            int* __restrict__ ssrc, float* __restrict__ snorm, int e) {
    int g = blockIdx.x * blockDim.x + threadIdx.x;
    if (g >= e) return;
    int s = src[g], d = dst[g];
    int pos = atomicAdd(&cursor[d], 1);
    ssrc[pos]  = s;
    snorm[pos] = dinv[s] * dinv[d];
}

// ---------------- MLP layer 1 (K=3) ----------------

__global__ void mlp1_kernel(const float* __restrict__ x, const float* __restrict__ w1,
                            const float* __restrict__ b1, float* __restrict__ h1, int n) {
    int gid = blockIdx.x * blockDim.x + threadIdx.x;
    if (gid >= n * 32) return;
    int node = gid >> 5, j = gid & 31;
    float x0 = x[node * 3 + 0], x1 = x[node * 3 + 1], x2 = x[node * 3 + 2];
    float v = b1[j] + x0 * w1[j] + x1 * w1[32 + j] + x2 * w1[64 + j];
    h1[gid] = fmaxf(v, 0.0f);
}

// ---------------- pad g3w [512,50] -> [512,64] (zero cols 50..63) -----------

__global__ void padw_kernel(const float* __restrict__ w, float* __restrict__ wp) {
    int gid = blockIdx.x * blockDim.x + threadIdx.x;   // 512*64
    if (gid >= 512 * 64) return;
    int r = gid >> 6, c = gid & 63;
    wp[gid] = (c < 50) ? w[r * 50 + c] : 0.0f;
}

// ---------------- 64x64-tile GEMM (N%64==0, K%16==0 path used) --------------

template<bool BIAS, bool RELU>
__global__ __launch_bounds__(256) void gemm64_kernel(
        const float* __restrict__ A, const float* __restrict__ B,
        const float* __restrict__ bias, float* __restrict__ C,
        int M, int N, int K) {
    __shared__ float As[16][68];
    __shared__ float Bs[16][68];
    const int tid = threadIdx.x;
    const int tx = tid & 15, ty = tid >> 4;
    const int bm = blockIdx.y * 64, bn = blockIdx.x * 64;

    float acc[4][4];
#pragma unroll
    for (int i = 0; i < 4; i++)
#pragma unroll
        for (int j = 0; j < 4; j++) acc[i][j] = 0.0f;

    for (int k0 = 0; k0 < K; k0 += 16) {
        {
            int m  = tid >> 2;
            int kq = (tid & 3) * 4;
            int gm = bm + m;
            float4 av = make_float4(0.f, 0.f, 0.f, 0.f);
            if (gm < M) av = *(const float4*)&A[(size_t)gm * K + k0 + kq];
            As[kq + 0][m] = av.x; As[kq + 1][m] = av.y;
            As[kq + 2][m] = av.z; As[kq + 3][m] = av.w;
        }
        {
            int kb = tid >> 4;
            int nb = (tid & 15) * 4;
            float4 bv = *(const float4*)&B[(size_t)(k0 + kb) * N + bn + nb];
            *(float4*)&Bs[kb][nb] = bv;
        }
        __syncthreads();

#pragma unroll
        for (int kk = 0; kk < 16; kk++) {
            float4 a4 = *(const float4*)&As[kk][ty * 4];
            float4 b4 = *(const float4*)&Bs[kk][tx * 4];
            float av[4] = {a4.x, a4.y, a4.z, a4.w};
            float bv[4] = {b4.x, b4.y, b4.z, b4.w};
#pragma unroll
            for (int i = 0; i < 4; i++)
#pragma unroll
                for (int j = 0; j < 4; j++)
                    acc[i][j] = fmaf(av[i], bv[j], acc[i][j]);
        }
        __syncthreads();
    }

#pragma unroll
    for (int i = 0; i < 4; i++) {
        int gm = bm + ty * 4 + i;
        if (gm >= M) continue;
#pragma unroll
        for (int j = 0; j < 4; j++) {
            int gn = bn + tx * 4 + j;
            float v = acc[i][j];
            if (BIAS) v += bias[gn];
            if (RELU) v = fmaxf(v, 0.0f);
            C[(size_t)gm * N + gn] = v;
        }
    }
}

// ---------------- 128x128-tile GEMM (N%128==0, K%16==0) ---------------------
// 256 threads, 8x8 micro-tile: 64 FMA per 4 ds_read_b128 per k-step.

template<bool BIAS, bool RELU>
__global__ __launch_bounds__(256) void gemm128_kernel(
        const float* __restrict__ A, const float* __restrict__ B,
        const float* __restrict__ bias, float* __restrict__ C,
        int M, int N, int K) {
    __shared__ float As[16][132];
    __shared__ float Bs[16][132];
    const int tid = threadIdx.x;
    const int tx = tid & 15, ty = tid >> 4;
    const int bm = blockIdx.y * 128, bn = blockIdx.x * 128;

    float acc[8][8];
#pragma unroll
    for (int i = 0; i < 8; i++)
#pragma unroll
        for (int j = 0; j < 8; j++) acc[i][j] = 0.0f;

    for (int k0 = 0; k0 < K; k0 += 16) {
        // A tile: 128 rows x 16 k = 512 float4; 2 per thread (transpose to As[k][m])
#pragma unroll
        for (int i = 0; i < 2; i++) {
            int t = i * 256 + tid;
            int m = t >> 2;
            int kq = (t & 3) * 4;
            int gm = bm + m;
            float4 av = make_float4(0.f, 0.f, 0.f, 0.f);
            if (gm < M) av = *(const float4*)&A[(size_t)gm * K + k0 + kq];
            As[kq + 0][m] = av.x; As[kq + 1][m] = av.y;
            As[kq + 2][m] = av.z; As[kq + 3][m] = av.w;
        }
        // B tile: 16 k x 128 n = 512 float4; 2 per thread
#pragma unroll
        for (int i = 0; i < 2; i++) {
            int t = i * 256 + tid;
            int kb = t >> 5;
            int nb = (t & 31) * 4;
            float4 bv = *(const float4*)&B[(size_t)(k0 + kb) * N + bn + nb];
            *(float4*)&Bs[kb][nb] = bv;
        }
        __syncthreads();

#pragma unroll
        for (int kk = 0; kk < 16; kk++) {
            float a[8], b[8];
            *(float4*)&a[0] = *(const float4*)&As[kk][ty * 8];
            *(float4*)&a[4] = *(const float4*)&As[kk][ty * 8 + 4];
            *(float4*)&b[0] = *(const float4*)&Bs[kk][tx * 8];
            *(float4*)&b[4] = *(const float4*)&Bs[kk][tx * 8 + 4];
#pragma unroll
            for (int i = 0; i < 8; i++)
#pragma unroll
                for (int j = 0; j < 8; j++)
                    acc[i][j] = fmaf(a[i], b[j], acc[i][j]);
        }
        __syncthreads();
    }

#pragma unroll
    for (int i = 0; i < 8; i++) {
        int gm = bm + ty * 8 + i;
        if (gm >= M) continue;
#pragma unroll
        for (int j4 = 0; j4 < 2; j4++) {
            int gn = bn + tx * 8 + j4 * 4;
            float4 v;
            v.x = acc[i][j4 * 4 + 0]; v.y = acc[i][j4 * 4 + 1];
            v.z = acc[i][j4 * 4 + 2]; v.w = acc[i][j4 * 4 + 3];
            if (BIAS) {
                v.x += bias[gn + 0]; v.y += bias[gn + 1];
                v.z += bias[gn + 2]; v.w += bias[gn + 3];
            }
            if (RELU) {
                v.x = fmaxf(v.x, 0.f); v.y = fmaxf(v.y, 0.f);
                v.z = fmaxf(v.z, 0.f); v.w = fmaxf(v.w, 0.f);
            }
            *(float4*)&C[(size_t)gm * N + gn] = v;
        }
    }
}

// ---------------- vectorized aggregation: thread per (node, float4-chunk) ---
// out[node] = sum_e norm_e * h[src_e] + h[node]*dinv[node]^2   (no bias/relu)

template<int F>
__global__ void agg_vec_kernel(const float* __restrict__ hw,
                               const int* __restrict__ offsets,
                               const int* __restrict__ ssrc,
                               const float* __restrict__ snorm,
                               const float* __restrict__ dinv,
                               float* __restrict__ out, int n) {
    constexpr int F4 = F / 4;
    int gid = blockIdx.x * blockDim.x + threadIdx.x;
    if (gid >= n * F4) return;
    int node = gid / F4;           // F4 is power of two -> shift
    int c4 = (gid - node * F4) * 4;

    float4 acc = make_float4(0.f, 0.f, 0.f, 0.f);
    int beg = offsets[node], end = offsets[node + 1];
    for (int e = beg; e < end; ++e) {
        int s = ssrc[e];
        float w = snorm[e];
        float4 r = *(const float4*)&hw[(size_t)s * F + c4];
        acc.x = fmaf(r.x, w, acc.x); acc.y = fmaf(r.y, w, acc.y);
        acc.z = fmaf(r.z, w, acc.z); acc.w = fmaf(r.w, w, acc.w);
    }
    float dv = dinv[node];
    float sw = dv * dv;
    float4 r = *(const float4*)&hw[(size_t)node * F + c4];
    acc.x = fmaf(r.x, sw, acc.x); acc.y = fmaf(r.y, sw, acc.y);
    acc.z = fmaf(r.z, sw, acc.z); acc.w = fmaf(r.w, sw, acc.w);
    *(float4*)&out[(size_t)node * F + c4] = acc;
}

// ---------------- final aggregation: stride-64 input -> stride-50 out + bias

__global__ void agg50_kernel(const float* __restrict__ z,
                             const int* __restrict__ offsets,
                             const int* __restrict__ ssrc,
                             const float* __restrict__ snorm,
                             const float* __restrict__ dinv,
                             const float* __restrict__ bias,
                             float* __restrict__ out, int n) {
    int gid = blockIdx.x * blockDim.x + threadIdx.x;
    int node = gid >> 6, f = gid & 63;
    if (node >= n || f >= 50) return;
    float acc = 0.0f;
    int beg = offsets[node], end = offsets[node + 1];
    for (int e = beg; e < end; ++e) {
        int s = ssrc[e];
        acc = fmaf(z[(size_t)s * 64 + f], snorm[e], acc);
    }
    float dv = dinv[node];
    acc = fmaf(z[(size_t)node * 64 + f], dv * dv, acc);
    out[(size_t)node * 50 + f] = acc + bias[f];
}

// ---------------- softmax over 50 features, one wave per node ---------------

__global__ void softmax_kernel(float* __restrict__ out, int n) {
    int node = blockIdx.x * 4 + (threadIdx.x >> 6);
    int lane = threadIdx.x & 63;
    if (node >= n) return;
    float v = (lane < 50) ? out[node * 50 + lane] : -INFINITY;
    float m = v;
#pragma unroll
    for (int off = 32; off > 0; off >>= 1) m = fmaxf(m, __shfl_xor(m, off));
    float e = (lane < 50) ? expf(v - m) : 0.0f;
    float s = e;
#pragma unroll
    for (int off = 32; off > 0; off >>= 1) s += __shfl_xor(s, off);
    if (lane < 50) out[node * 50 + lane] = e / s;
}

// ---------------------------------------------------------------------------

extern "C" void kernel_launch(void* const* d_in, const int* in_sizes, int n_in,
                              void* d_out, int out_size, void* d_ws, size_t ws_size,
                              hipStream_t stream) {
    const float* x    = (const float*)d_in[0];
    const int*   ei   = (const int*)  d_in[1];
    const float* w1   = (const float*)d_in[2];
    const float* b1   = (const float*)d_in[3];
    const float* w2   = (const float*)d_in[4];
    const float* b2   = (const float*)d_in[5];
    const float* w3   = (const float*)d_in[6];
    const float* b3   = (const float*)d_in[7];
    const float* g1w  = (const float*)d_in[8];
    const float* g1b  = (const float*)d_in[9];
    const float* g2w  = (const float*)d_in[10];
    const float* g2b  = (const float*)d_in[11];
    const float* g3w  = (const float*)d_in[12];
    const float* g3b  = (const float*)d_in[13];
    float* out = (float*)d_out;

    const int N = in_sizes[0] / 3;      // 50000
    const int E = in_sizes[1] / 2;      // 800000
    const int* src = ei;
    const int* dst = ei + E;

    // workspace arena (256B-aligned slots)
    char* ws = (char*)d_ws;
    size_t off = 0;
    auto alloc = [&](size_t bytes) -> char* {
        char* p = ws + off;
        off = (off + bytes + 255) & ~(size_t)255;
        return p;
    };
    int*   counts  = (int*)  alloc((size_t)N * 4);
    int*   offsets = (int*)  alloc((size_t)(N + 1) * 4);
    int*   cursor  = (int*)  alloc((size_t)N * 4);
    float* dinv    = (float*)alloc((size_t)N * 4);
    int*   ssrc    = (int*)  alloc((size_t)E * 4);
    float* snorm   = (float*)alloc((size_t)E * 4);
    float* wpad    = (float*)alloc((size_t)512 * 64 * 4);
    float* S128    = (float*)alloc((size_t)N * 128 * 4);   // 25.6 MB
    float* SA      = (float*)alloc((size_t)N * 512 * 4);   // 102.4 MB
    float* SB      = (float*)alloc((size_t)N * 512 * 4);   // 102.4 MB
    (void)ws_size;

    // ---- degree + CSR ----
    hipMemsetAsync(counts, 0, (size_t)N * 4, stream);
    hist_kernel<<<(E + 255) / 256, 256, 0, stream>>>(dst, counts, E);
    dinv_kernel<<<(N + 255) / 256, 256, 0, stream>>>(counts, dinv, N);
    scan_kernel<<<1, 1024, 0, stream>>>(counts, offsets, cursor, N);
    fill_kernel<<<(E + 255) / 256, 256, 0, stream>>>(src, dst, dinv, cursor, ssrc, snorm, E);
    padw_kernel<<<(512 * 64 + 255) / 256, 256, 0, stream>>>(g3w, wpad);

    // ---- MLP ----
    // h1 [N,32] -> SA
    mlp1_kernel<<<((size_t)N * 32 + 255) / 256, 256, 0, stream>>>(x, w1, b1, SA, N);
    {   // h2 = relu(h1 @ w2 + b2): K=32, N=64 -> SB
        dim3 grid(1, (N + 63) / 64);
        gemm64_kernel<true, true><<<grid, 256, 0, stream>>>(SA, w2, b2, SB, N, 64, 32);
    }
    {   // h3 = relu(h2 @ w3 + b3): K=64, N=128 -> S128
        dim3 grid(1, (N + 127) / 128);
        gemm128_kernel<true, true><<<grid, 256, 0, stream>>>(SB, w3, b3, S128, N, 128, 64);
    }

    // ---- GCN layer 1: agg@128 then GEMM 128->256 (+bias,relu) ----
    agg_vec_kernel<128><<<((size_t)N * 32 + 255) / 256, 256, 0, stream>>>(
        S128, offsets, ssrc, snorm, dinv, SA, N);
    {
        dim3 grid(256 / 128, (N + 127) / 128);
        gemm128_kernel<true, true><<<grid, 256, 0, stream>>>(SA, g1w, g1b, SB, N, 256, 128);
    }

    // ---- GCN layer 2: agg@256 then GEMM 256->512 (+bias,relu) ----
    agg_vec_kernel<256><<<((size_t)N * 64 + 255) / 256, 256, 0, stream>>>(
        SB, offsets, ssrc, snorm, dinv, SA, N);
    {
        dim3 grid(512 / 128, (N + 127) / 128);
        gemm128_kernel<true, true><<<grid, 256, 0, stream>>>(SA, g2w, g2b, SB, N, 512, 256);
    }

    // ---- GCN layer 3: GEMM 512->64(padded) then agg@50 (+bias) ----
    {
        dim3 grid(1, (N + 63) / 64);
        gemm64_kernel<false, false><<<grid, 256, 0, stream>>>(SB, wpad, nullptr, SA, N, 64, 512);
    }
    agg50_kernel<<<((size_t)N * 64 + 255) / 256, 256, 0, stream>>>(
        SA, offsets, ssrc, snorm, dinv, g3b, out, N);

    // ---- softmax ----
    softmax_kernel<<<(N + 3) / 4, 256, 0, stream>>>(out, N);
}

// Round 3
// 766.825 us; speedup vs baseline: 1.4005x; 1.0852x over previous
//
#include <hip/hip_runtime.h>
#include <hip/hip_bf16.h>
#include <math.h>

// ---------------------------------------------------------------------------
// GCN part-seg pipeline.
// R3: GCN GEMMs on bf16 matrix cores via double-bf16 emulation:
//     A = Ah + Al (bf16 split), C = Ah*Bh + Ah*Bl + Al*Bh  ==  one bf16 GEMM
//     with K' = 3K, A' = [Ah|Ah|Al] (virtual), B' = [Bh;Bl;Bh] (pre-split).
//     Splits fused into aggregation / GEMM epilogues (zero extra traffic).
// ---------------------------------------------------------------------------

typedef __attribute__((ext_vector_type(8))) short short8;     // 8 bf16
typedef __attribute__((ext_vector_type(4))) float floatx4;    // 4 fp32

__device__ __forceinline__ unsigned short bf16h(float f) {
    unsigned int u = __float_as_uint(f);
    u += 0x7fff + ((u >> 16) & 1);          // round-to-nearest-even
    return (unsigned short)(u >> 16);
}
__device__ __forceinline__ float bf16f(unsigned short h) {
    return __uint_as_float(((unsigned int)h) << 16);
}

// ---------------- degree / CSR build ----------------

__global__ void hist_kernel(const int* __restrict__ dst, int* __restrict__ counts, int e) {
    int g = blockIdx.x * blockDim.x + threadIdx.x;
    if (g < e) atomicAdd(&counts[dst[g]], 1);
}

__global__ void dinv_kernel(const int* __restrict__ counts, float* __restrict__ dinv, int n) {
    int g = blockIdx.x * blockDim.x + threadIdx.x;
    if (g < n) dinv[g] = rsqrtf((float)counts[g] + 1.0f);
}

__global__ void scan_kernel(const int* __restrict__ counts, int* __restrict__ offsets,
                            int* __restrict__ cursor, int n) {
    __shared__ int buf[1024];
    __shared__ int carry;
    int tid = threadIdx.x;
    if (tid == 0) carry = 0;
    __syncthreads();
    for (int base = 0; base < n; base += 1024) {
        int i = base + tid;
        int v = (i < n) ? counts[i] : 0;
        buf[tid] = v;
        __syncthreads();
        for (int off = 1; off < 1024; off <<= 1) {
            int t = (tid >= off) ? buf[tid - off] : 0;
            __syncthreads();
            buf[tid] += t;
            __syncthreads();
        }
        int excl = carry + buf[tid] - v;
        if (i < n) { offsets[i] = excl; cursor[i] = excl; }
        __syncthreads();
        if (tid == 0) carry += buf[1023];
        __syncthreads();
    }
    if (tid == 0) offsets[n] = carry;
}

__global__ void fill_kernel(const int* __restrict__ src, const int* __restrict__ dst,
                            const float* __restrict__ dinv, int* __restrict__ cursor,
                            int* __restrict__ ssrc, float* __restrict__ snorm, int e) {
    int g = blockIdx.x * blockDim.x + threadIdx.x;
    if (g >= e) return;
    int s = src[g], d = dst[g];
    int pos = atomicAdd(&cursor[d], 1);
    ssrc[pos]  = s;
    snorm[pos] = dinv[s] * dinv[d];
}

// ---------------- MLP layer 1 (K=3) ----------------

__global__ void mlp1_kernel(const float* __restrict__ x, const float* __restrict__ w1,
                            const float* __restrict__ b1, float* __restrict__ h1, int n) {
    int gid = blockIdx.x * blockDim.x + threadIdx.x;
    if (gid >= n * 32) return;
    int node = gid >> 5, j = gid & 31;
    float x0 = x[node * 3 + 0], x1 = x[node * 3 + 1], x2 = x[node * 3 + 2];
    float v = b1[j] + x0 * w1[j] + x1 * w1[32 + j] + x2 * w1[64 + j];
    h1[gid] = fmaxf(v, 0.0f);
}

// ---------------- pad g3w [512,50] -> [512,64] ----------------

__global__ void padw_kernel(const float* __restrict__ w, float* __restrict__ wp) {
    int gid = blockIdx.x * blockDim.x + threadIdx.x;
    if (gid >= 512 * 64) return;
    int r = gid >> 6, c = gid & 63;
    wp[gid] = (c < 50) ? w[r * 50 + c] : 0.0f;
}

// ---------------- weight split+transpose: W[K][N] fp32 -> Bt[N][3K] bf16 ----
// rows of Bt: k' in [0,K)=hi, [K,2K)=lo, [2K,3K)=hi  (pairs with A'=[Ah|Ah|Al]
// being wrong order? no: A' cols [Ah|Ah|Al] x B' rows [Bh;Bl;Bh] =
// AhBh + AhBl + AlBh  -- correct.)

__global__ void wsplit_kernel(const float* __restrict__ W, unsigned short* __restrict__ Bt,
                              int K, int N) {
    int gid = blockIdx.x * blockDim.x + threadIdx.x;
    if (gid >= K * N) return;
    int k = gid / N, n = gid - k * N;
    float w = W[(size_t)k * N + n];
    unsigned short h = bf16h(w);
    unsigned short l = bf16h(w - bf16f(h));
    size_t base = (size_t)n * (3 * K);
    Bt[base + k]         = h;
    Bt[base + K + k]     = l;
    Bt[base + 2 * K + k] = h;
}

// ---------------- fp32 tiled GEMMs for the tiny MLP layers ------------------

template<bool BIAS, bool RELU>
__global__ __launch_bounds__(256) void gemm64_kernel(
        const float* __restrict__ A, const float* __restrict__ B,
        const float* __restrict__ bias, float* __restrict__ C,
        int M, int N, int K) {
    __shared__ float As[16][68];
    __shared__ float Bs[16][68];
    const int tid = threadIdx.x;
    const int tx = tid & 15, ty = tid >> 4;
    const int bm = blockIdx.y * 64, bn = blockIdx.x * 64;

    float acc[4][4];
#pragma unroll
    for (int i = 0; i < 4; i++)
#pragma unroll
        for (int j = 0; j < 4; j++) acc[i][j] = 0.0f;

    for (int k0 = 0; k0 < K; k0 += 16) {
        {
            int m  = tid >> 2;
            int kq = (tid & 3) * 4;
            int gm = bm + m;
            float4 av = make_float4(0.f, 0.f, 0.f, 0.f);
            if (gm < M) av = *(const float4*)&A[(size_t)gm * K + k0 + kq];
            As[kq + 0][m] = av.x; As[kq + 1][m] = av.y;
            As[kq + 2][m] = av.z; As[kq + 3][m] = av.w;
        }
        {
            int kb = tid >> 4;
            int nb = (tid & 15) * 4;
            float4 bv = *(const float4*)&B[(size_t)(k0 + kb) * N + bn + nb];
            *(float4*)&Bs[kb][nb] = bv;
        }
        __syncthreads();
#pragma unroll
        for (int kk = 0; kk < 16; kk++) {
            float4 a4 = *(const float4*)&As[kk][ty * 4];
            float4 b4 = *(const float4*)&Bs[kk][tx * 4];
            float av[4] = {a4.x, a4.y, a4.z, a4.w};
            float bv[4] = {b4.x, b4.y, b4.z, b4.w};
#pragma unroll
            for (int i = 0; i < 4; i++)
#pragma unroll
                for (int j = 0; j < 4; j++)
                    acc[i][j] = fmaf(av[i], bv[j], acc[i][j]);
        }
        __syncthreads();
    }
#pragma unroll
    for (int i = 0; i < 4; i++) {
        int gm = bm + ty * 4 + i;
        if (gm >= M) continue;
#pragma unroll
        for (int j = 0; j < 4; j++) {
            int gn = bn + tx * 4 + j;
            float v = acc[i][j];
            if (BIAS) v += bias[gn];
            if (RELU) v = fmaxf(v, 0.0f);
            C[(size_t)gm * N + gn] = v;
        }
    }
}

template<bool BIAS, bool RELU>
__global__ __launch_bounds__(256) void gemm128_kernel(
        const float* __restrict__ A, const float* __restrict__ B,
        const float* __restrict__ bias, float* __restrict__ C,
        int M, int N, int K) {
    __shared__ float As[16][132];
    __shared__ float Bs[16][132];
    const int tid = threadIdx.x;
    const int tx = tid & 15, ty = tid >> 4;
    const int bm = blockIdx.y * 128, bn = blockIdx.x * 128;

    float acc[8][8];
#pragma unroll
    for (int i = 0; i < 8; i++)
#pragma unroll
        for (int j = 0; j < 8; j++) acc[i][j] = 0.0f;

    for (int k0 = 0; k0 < K; k0 += 16) {
#pragma unroll
        for (int i = 0; i < 2; i++) {
            int t = i * 256 + tid;
            int m = t >> 2;
            int kq = (t & 3) * 4;
            int gm = bm + m;
            float4 av = make_float4(0.f, 0.f, 0.f, 0.f);
            if (gm < M) av = *(const float4*)&A[(size_t)gm * K + k0 + kq];
            As[kq + 0][m] = av.x; As[kq + 1][m] = av.y;
            As[kq + 2][m] = av.z; As[kq + 3][m] = av.w;
        }
#pragma unroll
        for (int i = 0; i < 2; i++) {
            int t = i * 256 + tid;
            int kb = t >> 5;
            int nb = (t & 31) * 4;
            float4 bv = *(const float4*)&B[(size_t)(k0 + kb) * N + bn + nb];
            *(float4*)&Bs[kb][nb] = bv;
        }
        __syncthreads();
#pragma unroll
        for (int kk = 0; kk < 16; kk++) {
            float a[8], b[8];
            *(float4*)&a[0] = *(const float4*)&As[kk][ty * 8];
            *(float4*)&a[4] = *(const float4*)&As[kk][ty * 8 + 4];
            *(float4*)&b[0] = *(const float4*)&Bs[kk][tx * 8];
            *(float4*)&b[4] = *(const float4*)&Bs[kk][tx * 8 + 4];
#pragma unroll
            for (int i = 0; i < 8; i++)
#pragma unroll
                for (int j = 0; j < 8; j++)
                    acc[i][j] = fmaf(a[i], b[j], acc[i][j]);
        }
        __syncthreads();
    }
#pragma unroll
    for (int i = 0; i < 8; i++) {
        int gm = bm + ty * 8 + i;
        if (gm >= M) continue;
#pragma unroll
        for (int j4 = 0; j4 < 2; j4++) {
            int gn = bn + tx * 8 + j4 * 4;
            float4 v;
            v.x = acc[i][j4 * 4 + 0]; v.y = acc[i][j4 * 4 + 1];
            v.z = acc[i][j4 * 4 + 2]; v.w = acc[i][j4 * 4 + 3];
            if (BIAS) {
                v.x += bias[gn + 0]; v.y += bias[gn + 1];
                v.z += bias[gn + 2]; v.w += bias[gn + 3];
            }
            if (RELU) {
                v.x = fmaxf(v.x, 0.f); v.y = fmaxf(v.y, 0.f);
                v.z = fmaxf(v.z, 0.f); v.w = fmaxf(v.w, 0.f);
            }
            *(float4*)&C[(size_t)gm * N + gn] = v;
        }
    }
}

// ---------------- MFMA GEMM with double-bf16 emulation ----------------------
// C[M,N] = A[M,K](fp32, stored as Ah/Al bf16) @ B[K,N] (pre-split Bt[N][3K]).
// BM=128 rows/block, BN cols/block, BK=32. 256 threads = 4 waves.
// Wave grid WGR x WGC; per-wave frag grid WRF x WCF of 16x16 tiles.
// MODE 0: out fp32 = relu(C+bias).  MODE 1: relu(C+bias) split -> Ch/Cl bf16.
// MODE 2: out fp32 = C (no bias/relu).
// LDS layout: dim-major rows of 40 halves (80B) -> frag ds_read_b128 is
// 2-way-bank-aliased max (free, m136).

template<int BN, int WGR, int WGC, int WRF, int WCF, int MODE>
__global__ __launch_bounds__(256) void gemm_mfma_kernel(
        const unsigned short* __restrict__ Ah, const unsigned short* __restrict__ Al,
        const unsigned short* __restrict__ Bt, const float* __restrict__ bias,
        float* __restrict__ Cf, unsigned short* __restrict__ Ch,
        unsigned short* __restrict__ Cl, int M, int K, int N) {
    static_assert(WGR * WRF * 16 == 128, "row cover");
    static_assert(WGC * WCF * 16 == BN, "col cover");
    constexpr int AS = 40;                       // LDS row stride in halves
    __shared__ __align__(16) unsigned short As[128 * AS];
    __shared__ __align__(16) unsigned short Bs[BN * AS];

    const int tid  = threadIdx.x;
    const int lane = tid & 63;
    const int wave = tid >> 6;
    const int bm = blockIdx.y * 128;
    const int bn = blockIdx.x * BN;
    const int K3 = 3 * K;

    const int wr0 = (wave / WGC) * (WRF * 16);
    const int wc0 = (wave % WGC) * (WCF * 16);
    const int lr   = lane & 15;
    const int quad = lane >> 4;

    floatx4 acc[WRF][WCF];
#pragma unroll
    for (int i = 0; i < WRF; i++)
#pragma unroll
        for (int j = 0; j < WCF; j++) acc[i][j] = floatx4{0.f, 0.f, 0.f, 0.f};

    for (int k0 = 0; k0 < K3; k0 += 32) {
        // ---- stage A: 128 rows x 32 halves; segment-select Ah/Ah/Al ----
        {
            int seg = k0 / K;
            int kk  = k0 - seg * K;
            const unsigned short* Ap = (seg < 2) ? Ah : Al;
            int r = tid >> 1;
            int c = (tid & 1) << 4;              // 0 or 16 halves
            int gm = bm + r;
            uint4 v0 = make_uint4(0, 0, 0, 0), v1 = v0;
            if (gm < M) {
                const uint4* gp = reinterpret_cast<const uint4*>(
                    Ap + (size_t)gm * K + kk + c);
                v0 = gp[0]; v1 = gp[1];
            }
            unsigned short* d = &As[r * AS + c];
            *reinterpret_cast<uint4*>(d)     = v0;
            *reinterpret_cast<uint4*>(d + 8) = v1;
        }
        // ---- stage B from Bt[N][3K] ----
        if (BN == 128) {
            int r = tid >> 1;
            int c = (tid & 1) << 4;
            const uint4* gp = reinterpret_cast<const uint4*>(
                Bt + (size_t)(bn + r) * K3 + k0 + c);
            uint4 v0 = gp[0], v1 = gp[1];
            unsigned short* d = &Bs[r * AS + c];
            *reinterpret_cast<uint4*>(d)     = v0;
            *reinterpret_cast<uint4*>(d + 8) = v1;
        } else {                                  // BN == 64
            int r = tid >> 2;
            int c = (tid & 3) << 3;              // 0,8,16,24 halves
            const uint4* gp = reinterpret_cast<const uint4*>(
                Bt + (size_t)(bn + r) * K3 + k0 + c);
            uint4 v0 = gp[0];
            *reinterpret_cast<uint4*>(&Bs[r * AS + c]) = v0;
        }
        __syncthreads();

        // ---- fragments + MFMA ----
        short8 afr[WRF], bfr[WCF];
#pragma unroll
        for (int i = 0; i < WRF; i++)
            afr[i] = *reinterpret_cast<const short8*>(
                &As[(wr0 + i * 16 + lr) * AS + quad * 8]);
#pragma unroll
        for (int j = 0; j < WCF; j++)
            bfr[j] = *reinterpret_cast<const short8*>(
                &Bs[(wc0 + j * 16 + lr) * AS + quad * 8]);
#pragma unroll
        for (int i = 0; i < WRF; i++)
#pragma unroll
            for (int j = 0; j < WCF; j++)
                acc[i][j] = __builtin_amdgcn_mfma_f32_16x16x32_bf16(
                    afr[i], bfr[j], acc[i][j], 0, 0, 0);
        __syncthreads();
    }

    // ---- epilogue: C/D layout col=lane&15, row=quad*4+reg (m89-verified) ----
#pragma unroll
    for (int i = 0; i < WRF; i++) {
#pragma unroll
        for (int j = 0; j < WCF; j++) {
            int gc = bn + wc0 + j * 16 + lr;
#pragma unroll
            for (int reg = 0; reg < 4; reg++) {
                int gr = bm + wr0 + i * 16 + quad * 4 + reg;
                if (gr >= M) continue;
                float v = acc[i][j][reg];
                if (MODE == 0) {
                    v = fmaxf(v + bias[gc], 0.0f);
                    Cf[(size_t)gr * N + gc] = v;
                } else if (MODE == 1) {
                    v = fmaxf(v + bias[gc], 0.0f);
                    unsigned short h = bf16h(v);
                    unsigned short l = bf16h(v - bf16f(h));
                    Ch[(size_t)gr * N + gc] = h;
                    Cl[(size_t)gr * N + gc] = l;
                } else {
                    Cf[(size_t)gr * N + gc] = v;
                }
            }
        }
    }
}

// ---------------- aggregation (fp32 gather) with bf16 hi/lo split output ----

template<int F>
__global__ void agg_split_kernel(const float* __restrict__ hw,
                                 const int* __restrict__ offsets,
                                 const int* __restrict__ ssrc,
                                 const float* __restrict__ snorm,
                                 const float* __restrict__ dinv,
                                 unsigned short* __restrict__ Ah,
                                 unsigned short* __restrict__ Al, int n) {
    constexpr int F4 = F / 4;
    int gid = blockIdx.x * blockDim.x + threadIdx.x;
    if (gid >= n * F4) return;
    int node = gid / F4;
    int c4 = (gid - node * F4) * 4;

    float4 acc = make_float4(0.f, 0.f, 0.f, 0.f);
    int beg = offsets[node], end = offsets[node + 1];
    for (int e = beg; e < end; ++e) {
        int s = ssrc[e];
        float w = snorm[e];
        float4 r = *(const float4*)&hw[(size_t)s * F + c4];
        acc.x = fmaf(r.x, w, acc.x); acc.y = fmaf(r.y, w, acc.y);
        acc.z = fmaf(r.z, w, acc.z); acc.w = fmaf(r.w, w, acc.w);
    }
    float dv = dinv[node];
    float sw = dv * dv;
    float4 r = *(const float4*)&hw[(size_t)node * F + c4];
    acc.x = fmaf(r.x, sw, acc.x); acc.y = fmaf(r.y, sw, acc.y);
    acc.z = fmaf(r.z, sw, acc.z); acc.w = fmaf(r.w, sw, acc.w);

    float vals[4] = {acc.x, acc.y, acc.z, acc.w};
    ushort4 h4, l4;
    unsigned short* hp = (unsigned short*)&h4;
    unsigned short* lp = (unsigned short*)&l4;
#pragma unroll
    for (int t = 0; t < 4; t++) {
        unsigned short h = bf16h(vals[t]);
        hp[t] = h;
        lp[t] = bf16h(vals[t] - bf16f(h));
    }
    *(ushort4*)&Ah[(size_t)node * F + c4] = h4;
    *(ushort4*)&Al[(size_t)node * F + c4] = l4;
}

// ---------------- final aggregation: stride-64 fp32 in -> stride-50 + bias --

__global__ void agg50_kernel(const float* __restrict__ z,
                             const int* __restrict__ offsets,
                             const int* __restrict__ ssrc,
                             const float* __restrict__ snorm,
                             const float* __restrict__ dinv,
                             const float* __restrict__ bias,
                             float* __restrict__ out, int n) {
    int gid = blockIdx.x * blockDim.x + threadIdx.x;
    int node = gid >> 6, f = gid & 63;
    if (node >= n || f >= 50) return;
    float acc = 0.0f;
    int beg = offsets[node], end = offsets[node + 1];
    for (int e = beg; e < end; ++e) {
        int s = ssrc[e];
        acc = fmaf(z[(size_t)s * 64 + f], snorm[e], acc);
    }
    float dv = dinv[node];
    acc = fmaf(z[(size_t)node * 64 + f], dv * dv, acc);
    out[(size_t)node * 50 + f] = acc + bias[f];
}

// ---------------- softmax over 50 features, one wave per node ---------------

__global__ void softmax_kernel(float* __restrict__ out, int n) {
    int node = blockIdx.x * 4 + (threadIdx.x >> 6);
    int lane = threadIdx.x & 63;
    if (node >= n) return;
    float v = (lane < 50) ? out[node * 50 + lane] : -INFINITY;
    float m = v;
#pragma unroll
    for (int off = 32; off > 0; off >>= 1) m = fmaxf(m, __shfl_xor(m, off));
    float e = (lane < 50) ? expf(v - m) : 0.0f;
    float s = e;
#pragma unroll
    for (int off = 32; off > 0; off >>= 1) s += __shfl_xor(s, off);
    if (lane < 50) out[node * 50 + lane] = e / s;
}

// ---------------------------------------------------------------------------

extern "C" void kernel_launch(void* const* d_in, const int* in_sizes, int n_in,
                              void* d_out, int out_size, void* d_ws, size_t ws_size,
                              hipStream_t stream) {
    const float* x    = (const float*)d_in[0];
    const int*   ei   = (const int*)  d_in[1];
    const float* w1   = (const float*)d_in[2];
    const float* b1   = (const float*)d_in[3];
    const float* w2   = (const float*)d_in[4];
    const float* b2   = (const float*)d_in[5];
    const float* w3   = (const float*)d_in[6];
    const float* b3   = (const float*)d_in[7];
    const float* g1w  = (const float*)d_in[8];
    const float* g1b  = (const float*)d_in[9];
    const float* g2w  = (const float*)d_in[10];
    const float* g2b  = (const float*)d_in[11];
    const float* g3w  = (const float*)d_in[12];
    const float* g3b  = (const float*)d_in[13];
    float* out = (float*)d_out;

    const int N = in_sizes[0] / 3;      // 50000
    const int E = in_sizes[1] / 2;      // 800000
    const int* src = ei;
    const int* dst = ei + E;

    // ---- workspace arena with liveness-based region reuse (~214 MB) ----
    char* ws = (char*)d_ws;
    size_t off = 0;
    auto alloc = [&](size_t bytes) -> char* {
        char* p = ws + off;
        off = (off + bytes + 255) & ~(size_t)255;
        return p;
    };
    int*   counts  = (int*)  alloc((size_t)N * 4);
    int*   offsets = (int*)  alloc((size_t)(N + 1) * 4);
    int*   cursor  = (int*)  alloc((size_t)N * 4);
    float* dinv    = (float*)alloc((size_t)N * 4);
    int*   ssrc    = (int*)  alloc((size_t)E * 4);
    float* snorm   = (float*)alloc((size_t)E * 4);
    float* wpad    = (float*)alloc((size_t)512 * 64 * 4);
    unsigned short* Bt1 = (unsigned short*)alloc((size_t)256 * 384 * 2);
    unsigned short* Bt2 = (unsigned short*)alloc((size_t)512 * 768 * 2);
    unsigned short* Bt3 = (unsigned short*)alloc((size_t)64 * 1536 * 2);
    char* R1 = alloc((size_t)N * 256 * 4);   // 51.2 MB
    char* R2 = alloc((size_t)N * 256 * 4);   // 51.2 MB
    char* R3 = alloc((size_t)N * 512 * 4);   // 102.4 MB
    (void)ws_size;

    // R1 phase 1: S128 fp32 | A128h | A128l     R1 phase 2: A256h | A256l
    float*          S128  = (float*)R1;
    unsigned short* A128h = (unsigned short*)(R1 + (size_t)N * 128 * 4);
    unsigned short* A128l = (unsigned short*)(R1 + (size_t)N * 128 * 6);
    unsigned short* A256h = (unsigned short*)R1;
    unsigned short* A256l = (unsigned short*)(R1 + (size_t)N * 256 * 2);
    // R2 phase 1: SA32 | SB64      phase 2: G1 fp32 [N,256]   phase 3: z [N,64]
    float* SA32 = (float*)R2;
    float* SB64 = (float*)(R2 + (size_t)N * 32 * 4);
    float* G1   = (float*)R2;
    float* zbuf = (float*)R2;
    // R3: A512h | A512l
    unsigned short* A512h = (unsigned short*)R3;
    unsigned short* A512l = (unsigned short*)(R3 + (size_t)N * 512 * 2);

    // ---- degree + CSR + weight prep ----
    hipMemsetAsync(counts, 0, (size_t)N * 4, stream);
    hist_kernel<<<(E + 255) / 256, 256, 0, stream>>>(dst, counts, E);
    dinv_kernel<<<(N + 255) / 256, 256, 0, stream>>>(counts, dinv, N);
    scan_kernel<<<1, 1024, 0, stream>>>(counts, offsets, cursor, N);
    fill_kernel<<<(E + 255) / 256, 256, 0, stream>>>(src, dst, dinv, cursor, ssrc, snorm, E);
    padw_kernel<<<(512 * 64 + 255) / 256, 256, 0, stream>>>(g3w, wpad);
    wsplit_kernel<<<(128 * 256 + 255) / 256, 256, 0, stream>>>(g1w, Bt1, 128, 256);
    wsplit_kernel<<<(256 * 512 + 255) / 256, 256, 0, stream>>>(g2w, Bt2, 256, 512);
    wsplit_kernel<<<(512 * 64 + 255) / 256, 256, 0, stream>>>(wpad, Bt3, 512, 64);

    const int MB = (N + 127) / 128;     // 391 row-blocks

    // ---- MLP (fp32, tiny) ----
    mlp1_kernel<<<((size_t)N * 32 + 255) / 256, 256, 0, stream>>>(x, w1, b1, SA32, N);
    {   dim3 grid(1, (N + 63) / 64);
        gemm64_kernel<true, true><<<grid, 256, 0, stream>>>(SA32, w2, b2, SB64, N, 64, 32);
    }
    {   dim3 grid(1, MB);
        gemm128_kernel<true, true><<<grid, 256, 0, stream>>>(SB64, w3, b3, S128, N, 128, 64);
    }

    // ---- GCN1: agg@128 (split out) -> MFMA GEMM 128->256 (fp32 out) ----
    agg_split_kernel<128><<<((size_t)N * 32 + 255) / 256, 256, 0, stream>>>(
        S128, offsets, ssrc, snorm, dinv, A128h, A128l, N);
    {   dim3 grid(2, MB);
        gemm_mfma_kernel<128, 2, 2, 4, 4, 0><<<grid, 256, 0, stream>>>(
            A128h, A128l, Bt1, g1b, G1, nullptr, nullptr, N, 128, 256);
    }

    // ---- GCN2: agg@256 (split out) -> MFMA GEMM 256->512 (split out) ----
    agg_split_kernel<256><<<((size_t)N * 64 + 255) / 256, 256, 0, stream>>>(
        G1, offsets, ssrc, snorm, dinv, A256h, A256l, N);
    {   dim3 grid(4, MB);
        gemm_mfma_kernel<128, 2, 2, 4, 4, 1><<<grid, 256, 0, stream>>>(
            A256h, A256l, Bt2, g2b, nullptr, A512h, A512l, N, 256, 512);
    }

    // ---- GCN3: MFMA GEMM 512->64 (fp32 out) -> agg@50 (+bias) ----
    {   dim3 grid(1, MB);
        gemm_mfma_kernel<64, 4, 1, 2, 4, 2><<<grid, 256, 0, stream>>>(
            A512h, A512l, Bt3, nullptr, zbuf, nullptr, nullptr, N, 512, 64);
    }
    agg50_kernel<<<((size_t)N * 64 + 255) / 256, 256, 0, stream>>>(
        zbuf, offsets, ssrc, snorm, dinv, g3b, out, N);

    // ---- softmax ----
    softmax_kernel<<<(N + 3) / 4, 256, 0, stream>>>(out, N);
}

// Round 4
// 696.505 us; speedup vs baseline: 1.5419x; 1.1010x over previous
//
#include <hip/hip_runtime.h>
#include <hip/hip_bf16.h>
#include <math.h>

// ---------------------------------------------------------------------------
// GCN part-seg pipeline.
// R4: (1) agg kernels: wave-segment per node, shuffle-broadcast edge indices,
//     4-way unrolled independent accumulators (4 outstanding row gathers).
//     (2) MFMA GEMM staging via __builtin_amdgcn_global_load_lds width=16,
//     pad-free LDS (m97 structure).
// ---------------------------------------------------------------------------

typedef __attribute__((ext_vector_type(8))) short short8;     // 8 bf16
typedef __attribute__((ext_vector_type(4))) float floatx4;    // 4 fp32

__device__ __forceinline__ unsigned short bf16h(float f) {
    unsigned int u = __float_as_uint(f);
    u += 0x7fff + ((u >> 16) & 1);          // round-to-nearest-even
    return (unsigned short)(u >> 16);
}
__device__ __forceinline__ float bf16f(unsigned short h) {
    return __uint_as_float(((unsigned int)h) << 16);
}

__device__ __forceinline__ void gld_lds16(unsigned short* lds, const unsigned short* g) {
    __builtin_amdgcn_global_load_lds(
        (const __attribute__((address_space(1))) unsigned int*)g,
        (__attribute__((address_space(3))) unsigned int*)lds, 16, 0, 0);
}

// ---------------- degree / CSR build ----------------

__global__ void hist_kernel(const int* __restrict__ dst, int* __restrict__ counts, int e) {
    int g = blockIdx.x * blockDim.x + threadIdx.x;
    if (g < e) atomicAdd(&counts[dst[g]], 1);
}

__global__ void dinv_kernel(const int* __restrict__ counts, float* __restrict__ dinv, int n) {
    int g = blockIdx.x * blockDim.x + threadIdx.x;
    if (g < n) dinv[g] = rsqrtf((float)counts[g] + 1.0f);
}

__global__ void scan_kernel(const int* __restrict__ counts, int* __restrict__ offsets,
                            int* __restrict__ cursor, int n) {
    __shared__ int buf[1024];
    __shared__ int carry;
    int tid = threadIdx.x;
    if (tid == 0) carry = 0;
    __syncthreads();
    for (int base = 0; base < n; base += 1024) {
        int i = base + tid;
        int v = (i < n) ? counts[i] : 0;
        buf[tid] = v;
        __syncthreads();
        for (int off = 1; off < 1024; off <<= 1) {
            int t = (tid >= off) ? buf[tid - off] : 0;
            __syncthreads();
            buf[tid] += t;
            __syncthreads();
        }
        int excl = carry + buf[tid] - v;
        if (i < n) { offsets[i] = excl; cursor[i] = excl; }
        __syncthreads();
        if (tid == 0) carry += buf[1023];
        __syncthreads();
    }
    if (tid == 0) offsets[n] = carry;
}

__global__ void fill_kernel(const int* __restrict__ src, const int* __restrict__ dst,
                            const float* __restrict__ dinv, int* __restrict__ cursor,
                            int* __restrict__ ssrc, float* __restrict__ snorm, int e) {
    int g = blockIdx.x * blockDim.x + threadIdx.x;
    if (g >= e) return;
    int s = src[g], d = dst[g];
    int pos = atomicAdd(&cursor[d], 1);
    ssrc[pos]  = s;
    snorm[pos] = dinv[s] * dinv[d];
}

// ---------------- MLP layer 1 (K=3) ----------------

__global__ void mlp1_kernel(const float* __restrict__ x, const float* __restrict__ w1,
                            const float* __restrict__ b1, float* __restrict__ h1, int n) {
    int gid = blockIdx.x * blockDim.x + threadIdx.x;
    if (gid >= n * 32) return;
    int node = gid >> 5, j = gid & 31;
    float x0 = x[node * 3 + 0], x1 = x[node * 3 + 1], x2 = x[node * 3 + 2];
    float v = b1[j] + x0 * w1[j] + x1 * w1[32 + j] + x2 * w1[64 + j];
    h1[gid] = fmaxf(v, 0.0f);
}

// ---------------- pad g3w [512,50] -> [512,64] ----------------

__global__ void padw_kernel(const float* __restrict__ w, float* __restrict__ wp) {
    int gid = blockIdx.x * blockDim.x + threadIdx.x;
    if (gid >= 512 * 64) return;
    int r = gid >> 6, c = gid & 63;
    wp[gid] = (c < 50) ? w[r * 50 + c] : 0.0f;
}

// ---------------- weight split+transpose: W[K][N] fp32 -> Bt[N][3K] bf16 ----

__global__ void wsplit_kernel(const float* __restrict__ W, unsigned short* __restrict__ Bt,
                              int K, int N) {
    int gid = blockIdx.x * blockDim.x + threadIdx.x;
    if (gid >= K * N) return;
    int k = gid / N, n = gid - k * N;
    float w = W[(size_t)k * N + n];
    unsigned short h = bf16h(w);
    unsigned short l = bf16h(w - bf16f(h));
    size_t base = (size_t)n * (3 * K);
    Bt[base + k]         = h;
    Bt[base + K + k]     = l;
    Bt[base + 2 * K + k] = h;
}

// ---------------- fp32 tiled GEMMs for the tiny MLP layers ------------------

template<bool BIAS, bool RELU>
__global__ __launch_bounds__(256) void gemm64_kernel(
        const float* __restrict__ A, const float* __restrict__ B,
        const float* __restrict__ bias, float* __restrict__ C,
        int M, int N, int K) {
    __shared__ float As[16][68];
    __shared__ float Bs[16][68];
    const int tid = threadIdx.x;
    const int tx = tid & 15, ty = tid >> 4;
    const int bm = blockIdx.y * 64, bn = blockIdx.x * 64;

    float acc[4][4];
#pragma unroll
    for (int i = 0; i < 4; i++)
#pragma unroll
        for (int j = 0; j < 4; j++) acc[i][j] = 0.0f;

    for (int k0 = 0; k0 < K; k0 += 16) {
        {
            int m  = tid >> 2;
            int kq = (tid & 3) * 4;
            int gm = bm + m;
            float4 av = make_float4(0.f, 0.f, 0.f, 0.f);
            if (gm < M) av = *(const float4*)&A[(size_t)gm * K + k0 + kq];
            As[kq + 0][m] = av.x; As[kq + 1][m] = av.y;
            As[kq + 2][m] = av.z; As[kq + 3][m] = av.w;
        }
        {
            int kb = tid >> 4;
            int nb = (tid & 15) * 4;
            float4 bv = *(const float4*)&B[(size_t)(k0 + kb) * N + bn + nb];
            *(float4*)&Bs[kb][nb] = bv;
        }
        __syncthreads();
#pragma unroll
        for (int kk = 0; kk < 16; kk++) {
            float4 a4 = *(const float4*)&As[kk][ty * 4];
            float4 b4 = *(const float4*)&Bs[kk][tx * 4];
            float av[4] = {a4.x, a4.y, a4.z, a4.w};
            float bv[4] = {b4.x, b4.y, b4.z, b4.w};
#pragma unroll
            for (int i = 0; i < 4; i++)
#pragma unroll
                for (int j = 0; j < 4; j++)
                    acc[i][j] = fmaf(av[i], bv[j], acc[i][j]);
        }
        __syncthreads();
    }
#pragma unroll
    for (int i = 0; i < 4; i++) {
        int gm = bm + ty * 4 + i;
        if (gm >= M) continue;
#pragma unroll
        for (int j = 0; j < 4; j++) {
            int gn = bn + tx * 4 + j;
            float v = acc[i][j];
            if (BIAS) v += bias[gn];
            if (RELU) v = fmaxf(v, 0.0f);
            C[(size_t)gm * N + gn] = v;
        }
    }
}

template<bool BIAS, bool RELU>
__global__ __launch_bounds__(256) void gemm128_kernel(
        const float* __restrict__ A, const float* __restrict__ B,
        const float* __restrict__ bias, float* __restrict__ C,
        int M, int N, int K) {
    __shared__ float As[16][132];
    __shared__ float Bs[16][132];
    const int tid = threadIdx.x;
    const int tx = tid & 15, ty = tid >> 4;
    const int bm = blockIdx.y * 128, bn = blockIdx.x * 128;

    float acc[8][8];
#pragma unroll
    for (int i = 0; i < 8; i++)
#pragma unroll
        for (int j = 0; j < 8; j++) acc[i][j] = 0.0f;

    for (int k0 = 0; k0 < K; k0 += 16) {
#pragma unroll
        for (int i = 0; i < 2; i++) {
            int t = i * 256 + tid;
            int m = t >> 2;
            int kq = (t & 3) * 4;
            int gm = bm + m;
            float4 av = make_float4(0.f, 0.f, 0.f, 0.f);
            if (gm < M) av = *(const float4*)&A[(size_t)gm * K + k0 + kq];
            As[kq + 0][m] = av.x; As[kq + 1][m] = av.y;
            As[kq + 2][m] = av.z; As[kq + 3][m] = av.w;
        }
#pragma unroll
        for (int i = 0; i < 2; i++) {
            int t = i * 256 + tid;
            int kb = t >> 5;
            int nb = (t & 31) * 4;
            float4 bv = *(const float4*)&B[(size_t)(k0 + kb) * N + bn + nb];
            *(float4*)&Bs[kb][nb] = bv;
        }
        __syncthreads();
#pragma unroll
        for (int kk = 0; kk < 16; kk++) {
            float a[8], b[8];
            *(float4*)&a[0] = *(const float4*)&As[kk][ty * 8];
            *(float4*)&a[4] = *(const float4*)&As[kk][ty * 8 + 4];
            *(float4*)&b[0] = *(const float4*)&Bs[kk][tx * 8];
            *(float4*)&b[4] = *(const float4*)&Bs[kk][tx * 8 + 4];
#pragma unroll
            for (int i = 0; i < 8; i++)
#pragma unroll
                for (int j = 0; j < 8; j++)
                    acc[i][j] = fmaf(a[i], b[j], acc[i][j]);
        }
        __syncthreads();
    }
#pragma unroll
    for (int i = 0; i < 8; i++) {
        int gm = bm + ty * 8 + i;
        if (gm >= M) continue;
#pragma unroll
        for (int j4 = 0; j4 < 2; j4++) {
            int gn = bn + tx * 8 + j4 * 4;
            float4 v;
            v.x = acc[i][j4 * 4 + 0]; v.y = acc[i][j4 * 4 + 1];
            v.z = acc[i][j4 * 4 + 2]; v.w = acc[i][j4 * 4 + 3];
            if (BIAS) {
                v.x += bias[gn + 0]; v.y += bias[gn + 1];
                v.z += bias[gn + 2]; v.w += bias[gn + 3];
            }
            if (RELU) {
                v.x = fmaxf(v.x, 0.f); v.y = fmaxf(v.y, 0.f);
                v.z = fmaxf(v.z, 0.f); v.w = fmaxf(v.w, 0.f);
            }
            *(float4*)&C[(size_t)gm * N + gn] = v;
        }
    }
}

// ---------------- MFMA GEMM, double-bf16, global_load_lds staging -----------
// C[M,N] = (Ah+Al)[M,K] @ B[K,N], B pre-split as Bt[N][3K] = [Bh;Bl;Bh].
// A' = [Ah|Ah|Al] over K'=3K. BM=128, BK=32 halves. 256 threads = 4 waves.
// LDS: pad-free rows of 32 halves (64B) -> global_load_lds dest = wave-uniform
// base + lane*16B (16 rows per wave-instruction, contiguous).
// MODE 0: Cf = relu(C+bias). MODE 1: relu(C+bias) split -> Ch/Cl. MODE 2: Cf=C.

template<int BN, int WGR, int WGC, int WRF, int WCF, int MODE>
__global__ __launch_bounds__(256) void gemm_mfma_kernel(
        const unsigned short* __restrict__ Ah, const unsigned short* __restrict__ Al,
        const unsigned short* __restrict__ Bt, const float* __restrict__ bias,
        float* __restrict__ Cf, unsigned short* __restrict__ Ch,
        unsigned short* __restrict__ Cl, int M, int K, int N) {
    static_assert(WGR * WRF * 16 == 128, "row cover");
    static_assert(WGC * WCF * 16 == BN, "col cover");
    __shared__ __align__(16) unsigned short As[128 * 32];
    __shared__ __align__(16) unsigned short Bs[BN * 32];

    const int tid  = threadIdx.x;
    const int lane = tid & 63;
    const int wave = tid >> 6;
    const int bm = blockIdx.y * 128;
    const int bn = blockIdx.x * BN;
    const int K2 = 2 * K, K3 = 3 * K;

    const int wr0 = (wave / WGC) * (WRF * 16);
    const int wc0 = (wave % WGC) * (WCF * 16);
    const int lr   = lane & 15;
    const int quad = lane >> 4;
    const int arow = lane >> 2;          // row within 16-row group
    const int acol = (lane & 3) * 8;     // halves within 32-half row

    floatx4 acc[WRF][WCF];
#pragma unroll
    for (int i = 0; i < WRF; i++)
#pragma unroll
        for (int j = 0; j < WCF; j++) acc[i][j] = floatx4{0.f, 0.f, 0.f, 0.f};

    for (int k0 = 0; k0 < K3; k0 += 32) {
        const unsigned short* Ap; int kk;
        if (k0 < K)       { Ap = Ah; kk = k0; }
        else if (k0 < K2) { Ap = Ah; kk = k0 - K; }
        else              { Ap = Al; kk = k0 - K2; }

        // A: 128 rows x 32 halves = 8 groups of 16 rows; 2 per wave
#pragma unroll
        for (int i = 0; i < 2; i++) {
            int grp = wave * 2 + i;
            int gm = bm + grp * 16 + arow;
            if (gm >= M) gm = M - 1;     // clamp: garbage rows discarded at store
            gld_lds16(&As[grp * 512], Ap + (size_t)gm * K + kk + acol);
        }
        // B: BN rows x 32 halves; BN/64 per wave
#pragma unroll
        for (int i = 0; i < BN / 64; i++) {
            int grp = wave * (BN / 64) + i;
            int gr = bn + grp * 16 + arow;
            gld_lds16(&Bs[grp * 512], Bt + (size_t)gr * K3 + k0 + acol);
        }
        __syncthreads();

        short8 afr[WRF], bfr[WCF];
#pragma unroll
        for (int i = 0; i < WRF; i++)
            afr[i] = *reinterpret_cast<const short8*>(
                &As[(wr0 + i * 16 + lr) * 32 + quad * 8]);
#pragma unroll
        for (int j = 0; j < WCF; j++)
            bfr[j] = *reinterpret_cast<const short8*>(
                &Bs[(wc0 + j * 16 + lr) * 32 + quad * 8]);
#pragma unroll
        for (int i = 0; i < WRF; i++)
#pragma unroll
            for (int j = 0; j < WCF; j++)
                acc[i][j] = __builtin_amdgcn_mfma_f32_16x16x32_bf16(
                    afr[i], bfr[j], acc[i][j], 0, 0, 0);
        __syncthreads();
    }

    // epilogue: C/D layout col=lane&15, row=quad*4+reg (m89-verified)
#pragma unroll
    for (int i = 0; i < WRF; i++) {
#pragma unroll
        for (int j = 0; j < WCF; j++) {
            int gc = bn + wc0 + j * 16 + lr;
#pragma unroll
            for (int reg = 0; reg < 4; reg++) {
                int gr = bm + wr0 + i * 16 + quad * 4 + reg;
                if (gr >= M) continue;
                float v = acc[i][j][reg];
                if (MODE == 0) {
                    v = fmaxf(v + bias[gc], 0.0f);
                    Cf[(size_t)gr * N + gc] = v;
                } else if (MODE == 1) {
                    v = fmaxf(v + bias[gc], 0.0f);
                    unsigned short h = bf16h(v);
                    unsigned short l = bf16h(v - bf16f(h));
                    Ch[(size_t)gr * N + gc] = h;
                    Cl[(size_t)gr * N + gc] = l;
                } else {
                    Cf[(size_t)gr * N + gc] = v;
                }
            }
        }
    }
}

// ---------------- aggregation: wave-segment per node, 4-way unrolled --------
// CH = F/4 lanes per node. Lanes cooperatively load CH edge (idx,norm) pairs,
// shuffle-broadcast, gather 4 rows concurrently into independent accumulators.
// Output: bf16 hi/lo split (MFMA A operand).

template<int F>
__global__ void agg_split_kernel(const float* __restrict__ hw,
                                 const int* __restrict__ offsets,
                                 const int* __restrict__ ssrc,
                                 const float* __restrict__ snorm,
                                 const float* __restrict__ dinv,
                                 unsigned short* __restrict__ Ah,
                                 unsigned short* __restrict__ Al, int n) {
    constexpr int CH = F / 4;            // 64 (F=256) or 32 (F=128)
    int gtid = blockIdx.x * blockDim.x + threadIdx.x;
    int node = gtid / CH;
    if (node >= n) return;
    int sub = threadIdx.x & (CH - 1);
    int c4 = sub * 4;

    float4 a0 = make_float4(0.f, 0.f, 0.f, 0.f);
    float4 a1 = a0, a2 = a0, a3 = a0;

    int beg = offsets[node], end = offsets[node + 1];
    for (int base = beg; base < end; base += CH) {
        int idx = base + sub;
        int   myS = 0;
        float myW = 0.0f;
        if (idx < end) { myS = ssrc[idx]; myW = snorm[idx]; }
        int cnt = end - base; if (cnt > CH) cnt = CH;
        int cr = (cnt + 3) & ~3;
        for (int j = 0; j < cr; j += 4) {
            int s0 = __shfl(myS, j + 0, CH), s1 = __shfl(myS, j + 1, CH);
            int s2 = __shfl(myS, j + 2, CH), s3 = __shfl(myS, j + 3, CH);
            float w0 = __shfl(myW, j + 0, CH), w1 = __shfl(myW, j + 1, CH);
            float w2 = __shfl(myW, j + 2, CH), w3 = __shfl(myW, j + 3, CH);
            float4 r0 = *(const float4*)&hw[(size_t)s0 * F + c4];
            float4 r1 = *(const float4*)&hw[(size_t)s1 * F + c4];
            float4 r2 = *(const float4*)&hw[(size_t)s2 * F + c4];
            float4 r3 = *(const float4*)&hw[(size_t)s3 * F + c4];
            a0.x = fmaf(r0.x, w0, a0.x); a0.y = fmaf(r0.y, w0, a0.y);
            a0.z = fmaf(r0.z, w0, a0.z); a0.w = fmaf(r0.w, w0, a0.w);
            a1.x = fmaf(r1.x, w1, a1.x); a1.y = fmaf(r1.y, w1, a1.y);
            a1.z = fmaf(r1.z, w1, a1.z); a1.w = fmaf(r1.w, w1, a1.w);
            a2.x = fmaf(r2.x, w2, a2.x); a2.y = fmaf(r2.y, w2, a2.y);
            a2.z = fmaf(r2.z, w2, a2.z); a2.w = fmaf(r2.w, w2, a2.w);
            a3.x = fmaf(r3.x, w3, a3.x); a3.y = fmaf(r3.y, w3, a3.y);
            a3.z = fmaf(r3.z, w3, a3.z); a3.w = fmaf(r3.w, w3, a3.w);
        }
    }
    float dv = dinv[node];
    float sw = dv * dv;
    float4 r = *(const float4*)&hw[(size_t)node * F + c4];
    float4 a;
    a.x = fmaf(r.x, sw, a0.x + a1.x + a2.x + a3.x);
    a.y = fmaf(r.y, sw, a0.y + a1.y + a2.y + a3.y);
    a.z = fmaf(r.z, sw, a0.z + a1.z + a2.z + a3.z);
    a.w = fmaf(r.w, sw, a0.w + a1.w + a2.w + a3.w);

    float vals[4] = {a.x, a.y, a.z, a.w};
    ushort4 h4, l4;
    unsigned short* hp = (unsigned short*)&h4;
    unsigned short* lp = (unsigned short*)&l4;
#pragma unroll
    for (int t = 0; t < 4; t++) {
        unsigned short h = bf16h(vals[t]);
        hp[t] = h;
        lp[t] = bf16h(vals[t] - bf16f(h));
    }
    *(ushort4*)&Ah[(size_t)node * F + c4] = h4;
    *(ushort4*)&Al[(size_t)node * F + c4] = l4;
}

// ---------------- final aggregation: one wave/node, stride-64 in, 50 out ----

__global__ void agg50_kernel(const float* __restrict__ z,
                             const int* __restrict__ offsets,
                             const int* __restrict__ ssrc,
                             const float* __restrict__ snorm,
                             const float* __restrict__ dinv,
                             const float* __restrict__ bias,
                             float* __restrict__ out, int n) {
    int node = (blockIdx.x * blockDim.x + threadIdx.x) >> 6;
    int lane = threadIdx.x & 63;
    if (node >= n) return;

    float a0 = 0.f, a1 = 0.f, a2 = 0.f, a3 = 0.f;
    int beg = offsets[node], end = offsets[node + 1];
    for (int base = beg; base < end; base += 64) {
        int idx = base + lane;
        int   myS = 0;
        float myW = 0.0f;
        if (idx < end) { myS = ssrc[idx]; myW = snorm[idx]; }
        int cnt = end - base; if (cnt > 64) cnt = 64;
        int cr = (cnt + 3) & ~3;
        for (int j = 0; j < cr; j += 4) {
            int s0 = __shfl(myS, j + 0), s1 = __shfl(myS, j + 1);
            int s2 = __shfl(myS, j + 2), s3 = __shfl(myS, j + 3);
            float w0 = __shfl(myW, j + 0), w1 = __shfl(myW, j + 1);
            float w2 = __shfl(myW, j + 2), w3 = __shfl(myW, j + 3);
            a0 = fmaf(z[(size_t)s0 * 64 + lane], w0, a0);
            a1 = fmaf(z[(size_t)s1 * 64 + lane], w1, a1);
            a2 = fmaf(z[(size_t)s2 * 64 + lane], w2, a2);
            a3 = fmaf(z[(size_t)s3 * 64 + lane], w3, a3);
        }
    }
    float dv = dinv[node];
    float v = fmaf(z[(size_t)node * 64 + lane], dv * dv, a0 + a1 + a2 + a3);
    if (lane < 50) out[(size_t)node * 50 + lane] = v + bias[lane];
}

// ---------------- softmax over 50 features, one wave per node ---------------

__global__ void softmax_kernel(float* __restrict__ out, int n) {
    int node = blockIdx.x * 4 + (threadIdx.x >> 6);
    int lane = threadIdx.x & 63;
    if (node >= n) return;
    float v = (lane < 50) ? out[node * 50 + lane] : -INFINITY;
    float m = v;
#pragma unroll
    for (int off = 32; off > 0; off >>= 1) m = fmaxf(m, __shfl_xor(m, off));
    float e = (lane < 50) ? expf(v - m) : 0.0f;
    float s = e;
#pragma unroll
    for (int off = 32; off > 0; off >>= 1) s += __shfl_xor(s, off);
    if (lane < 50) out[node * 50 + lane] = e / s;
}

// ---------------------------------------------------------------------------

extern "C" void kernel_launch(void* const* d_in, const int* in_sizes, int n_in,
                              void* d_out, int out_size, void* d_ws, size_t ws_size,
                              hipStream_t stream) {
    const float* x    = (const float*)d_in[0];
    const int*   ei   = (const int*)  d_in[1];
    const float* w1   = (const float*)d_in[2];
    const float* b1   = (const float*)d_in[3];
    const float* w2   = (const float*)d_in[4];
    const float* b2   = (const float*)d_in[5];
    const float* w3   = (const float*)d_in[6];
    const float* b3   = (const float*)d_in[7];
    const float* g1w  = (const float*)d_in[8];
    const float* g1b  = (const float*)d_in[9];
    const float* g2w  = (const float*)d_in[10];
    const float* g2b  = (const float*)d_in[11];
    const float* g3w  = (const float*)d_in[12];
    const float* g3b  = (const float*)d_in[13];
    float* out = (float*)d_out;

    const int N = in_sizes[0] / 3;      // 50000
    const int E = in_sizes[1] / 2;      // 800000
    const int* src = ei;
    const int* dst = ei + E;

    // ---- workspace arena with liveness-based region reuse ----
    char* ws = (char*)d_ws;
    size_t off = 0;
    auto alloc = [&](size_t bytes) -> char* {
        char* p = ws + off;
        off = (off + bytes + 255) & ~(size_t)255;
        return p;
    };
    int*   counts  = (int*)  alloc((size_t)N * 4);
    int*   offsets = (int*)  alloc((size_t)(N + 1) * 4);
    int*   cursor  = (int*)  alloc((size_t)N * 4);
    float* dinv    = (float*)alloc((size_t)N * 4);
    int*   ssrc    = (int*)  alloc((size_t)E * 4);
    float* snorm   = (float*)alloc((size_t)E * 4);
    float* wpad    = (float*)alloc((size_t)512 * 64 * 4);
    unsigned short* Bt1 = (unsigned short*)alloc((size_t)256 * 384 * 2);
    unsigned short* Bt2 = (unsigned short*)alloc((size_t)512 * 768 * 2);
    unsigned short* Bt3 = (unsigned short*)alloc((size_t)64 * 1536 * 2);
    char* R1 = alloc((size_t)N * 256 * 4);   // 51.2 MB
    char* R2 = alloc((size_t)N * 256 * 4);   // 51.2 MB
    char* R3 = alloc((size_t)N * 512 * 4);   // 102.4 MB
    (void)ws_size;

    // R1 phase 1: S128 fp32 | A128h | A128l     R1 phase 2: A256h | A256l
    float*          S128  = (float*)R1;
    unsigned short* A128h = (unsigned short*)(R1 + (size_t)N * 128 * 4);
    unsigned short* A128l = (unsigned short*)(R1 + (size_t)N * 128 * 6);
    unsigned short* A256h = (unsigned short*)R1;
    unsigned short* A256l = (unsigned short*)(R1 + (size_t)N * 256 * 2);
    // R2 phase 1: SA32 | SB64      phase 2: G1 fp32 [N,256]   phase 3: z [N,64]
    float* SA32 = (float*)R2;
    float* SB64 = (float*)(R2 + (size_t)N * 32 * 4);
    float* G1   = (float*)R2;
    float* zbuf = (float*)R2;
    // R3: A512h | A512l
    unsigned short* A512h = (unsigned short*)R3;
    unsigned short* A512l = (unsigned short*)(R3 + (size_t)N * 512 * 2);

    // ---- degree + CSR + weight prep ----
    hipMemsetAsync(counts, 0, (size_t)N * 4, stream);
    hist_kernel<<<(E + 255) / 256, 256, 0, stream>>>(dst, counts, E);
    dinv_kernel<<<(N + 255) / 256, 256, 0, stream>>>(counts, dinv, N);
    scan_kernel<<<1, 1024, 0, stream>>>(counts, offsets, cursor, N);
    fill_kernel<<<(E + 255) / 256, 256, 0, stream>>>(src, dst, dinv, cursor, ssrc, snorm, E);
    padw_kernel<<<(512 * 64 + 255) / 256, 256, 0, stream>>>(g3w, wpad);
    wsplit_kernel<<<(128 * 256 + 255) / 256, 256, 0, stream>>>(g1w, Bt1, 128, 256);
    wsplit_kernel<<<(256 * 512 + 255) / 256, 256, 0, stream>>>(g2w, Bt2, 256, 512);
    wsplit_kernel<<<(512 * 64 + 255) / 256, 256, 0, stream>>>(wpad, Bt3, 512, 64);

    const int MB = (N + 127) / 128;     // 391 row-blocks

    // ---- MLP (fp32, tiny) ----
    mlp1_kernel<<<((size_t)N * 32 + 255) / 256, 256, 0, stream>>>(x, w1, b1, SA32, N);
    {   dim3 grid(1, (N + 63) / 64);
        gemm64_kernel<true, true><<<grid, 256, 0, stream>>>(SA32, w2, b2, SB64, N, 64, 32);
    }
    {   dim3 grid(1, MB);
        gemm128_kernel<true, true><<<grid, 256, 0, stream>>>(SB64, w3, b3, S128, N, 128, 64);
    }

    // ---- GCN1: agg@128 (split out) -> MFMA GEMM 128->256 (fp32 out) ----
    agg_split_kernel<128><<<((size_t)N * 32 + 255) / 256, 256, 0, stream>>>(
        S128, offsets, ssrc, snorm, dinv, A128h, A128l, N);
    {   dim3 grid(2, MB);
        gemm_mfma_kernel<128, 2, 2, 4, 4, 0><<<grid, 256, 0, stream>>>(
            A128h, A128l, Bt1, g1b, G1, nullptr, nullptr, N, 128, 256);
    }

    // ---- GCN2: agg@256 (split out) -> MFMA GEMM 256->512 (split out) ----
    agg_split_kernel<256><<<((size_t)N * 64 + 255) / 256, 256, 0, stream>>>(
        G1, offsets, ssrc, snorm, dinv, A256h, A256l, N);
    {   dim3 grid(4, MB);
        gemm_mfma_kernel<128, 2, 2, 4, 4, 1><<<grid, 256, 0, stream>>>(
            A256h, A256l, Bt2, g2b, nullptr, A512h, A512l, N, 256, 512);
    }

    // ---- GCN3: MFMA GEMM 512->64 (fp32 out) -> agg@50 (+bias) ----
    {   dim3 grid(1, MB);
        gemm_mfma_kernel<64, 4, 1, 2, 4, 2><<<grid, 256, 0, stream>>>(
            A512h, A512l, Bt3, nullptr, zbuf, nullptr, nullptr, N, 512, 64);
    }
    agg50_kernel<<<((size_t)N * 64 + 255) / 256, 256, 0, stream>>>(
        zbuf, offsets, ssrc, snorm, dinv, g3b, out, N);

    // ---- softmax ----
    softmax_kernel<<<(N + 3) / 4, 256, 0, stream>>>(out, N);
}

// Round 5
// 654.288 us; speedup vs baseline: 1.6414x; 1.0645x over previous
//
#include <hip/hip_runtime.h>
#include <hip/hip_bf16.h>
#include <math.h>

// ---------------------------------------------------------------------------
// GCN part-seg pipeline.
// R5: revert agg to R3 simple form (fabric-bound; ILP regressed); parallel
//     3-phase scan; fused MLP12 (x->h2); fused agg50+softmax; fused weight
//     prep. MFMA GEMMs (double-bf16, global_load_lds) kept from R4.
// ---------------------------------------------------------------------------

typedef __attribute__((ext_vector_type(8))) short short8;     // 8 bf16
typedef __attribute__((ext_vector_type(4))) float floatx4;    // 4 fp32

__device__ __forceinline__ unsigned short bf16h(float f) {
    unsigned int u = __float_as_uint(f);
    u += 0x7fff + ((u >> 16) & 1);          // round-to-nearest-even
    return (unsigned short)(u >> 16);
}
__device__ __forceinline__ float bf16f(unsigned short h) {
    return __uint_as_float(((unsigned int)h) << 16);
}

__device__ __forceinline__ void gld_lds16(unsigned short* lds, const unsigned short* g) {
    __builtin_amdgcn_global_load_lds(
        (const __attribute__((address_space(1))) unsigned int*)g,
        (__attribute__((address_space(3))) unsigned int*)lds, 16, 0, 0);
}

// ---------------- degree / CSR build ----------------

__global__ void hist_kernel(const int* __restrict__ dst, int* __restrict__ counts, int e) {
    int g = blockIdx.x * blockDim.x + threadIdx.x;
    if (g < e) atomicAdd(&counts[dst[g]], 1);
}

// 3-phase parallel scan over counts[n] (chunks of 256).
__global__ void scan1_kernel(const int* __restrict__ counts, int* __restrict__ bsum, int n) {
    __shared__ int buf[256];
    int i = blockIdx.x * 256 + threadIdx.x;
    buf[threadIdx.x] = (i < n) ? counts[i] : 0;
    __syncthreads();
    for (int off = 128; off > 0; off >>= 1) {
        if (threadIdx.x < off) buf[threadIdx.x] += buf[threadIdx.x + off];
        __syncthreads();
    }
    if (threadIdx.x == 0) bsum[blockIdx.x] = buf[0];
}

__global__ void scan2_kernel(const int* __restrict__ bsum, int* __restrict__ bsumx,
                             int* __restrict__ offsets, int nb, int n) {
    __shared__ int buf[256];
    int tid = threadIdx.x;
    int v = (tid < nb) ? bsum[tid] : 0;
    buf[tid] = v;
    __syncthreads();
    for (int off = 1; off < 256; off <<= 1) {
        int t = (tid >= off) ? buf[tid - off] : 0;
        __syncthreads();
        buf[tid] += t;
        __syncthreads();
    }
    if (tid < nb) bsumx[tid] = buf[tid] - v;       // exclusive
    if (tid == 255) offsets[n] = buf[255];          // total
}

__global__ void scan3_kernel(const int* __restrict__ counts, const int* __restrict__ bsumx,
                             int* __restrict__ offsets, int* __restrict__ cursor,
                             float* __restrict__ dinv, int n) {
    __shared__ int buf[256];
    int tid = threadIdx.x;
    int i = blockIdx.x * 256 + tid;
    int c = (i < n) ? counts[i] : 0;
    buf[tid] = c;
    __syncthreads();
    for (int off = 1; off < 256; off <<= 1) {
        int t = (tid >= off) ? buf[tid - off] : 0;
        __syncthreads();
        buf[tid] += t;
        __syncthreads();
    }
    if (i < n) {
        int excl = bsumx[blockIdx.x] + buf[tid] - c;
        offsets[i] = excl;
        cursor[i] = excl;
        dinv[i] = rsqrtf((float)c + 1.0f);
    }
}

__global__ void fill_kernel(const int* __restrict__ src, const int* __restrict__ dst,
                            const float* __restrict__ dinv, int* __restrict__ cursor,
                            int* __restrict__ ssrc, float* __restrict__ snorm, int e) {
    int g = blockIdx.x * blockDim.x + threadIdx.x;
    if (g >= e) return;
    int s = src[g], d = dst[g];
    int pos = atomicAdd(&cursor[d], 1);
    ssrc[pos]  = s;
    snorm[pos] = dinv[s] * dinv[d];
}

// ---------------- fused weight prep: split+transpose all three GCN weights --
// W[K][N] fp32 -> Bt[N][3K] bf16 rows [Bh;Bl;Bh]; g3w padded 50->64 cols.

__device__ __forceinline__ void wsplit_one(float w, unsigned short* Bt, int k, int n, int K) {
    unsigned short h = bf16h(w);
    unsigned short l = bf16h(w - bf16f(h));
    size_t base = (size_t)n * (3 * K);
    Bt[base + k]         = h;
    Bt[base + K + k]     = l;
    Bt[base + 2 * K + k] = h;
}

__global__ void prepw_kernel(const float* __restrict__ g1w, const float* __restrict__ g2w,
                             const float* __restrict__ g3w,
                             unsigned short* __restrict__ Bt1,
                             unsigned short* __restrict__ Bt2,
                             unsigned short* __restrict__ Bt3) {
    int gid = blockIdx.x * blockDim.x + threadIdx.x;
    if (gid < 32768) {                       // g1: K=128, N=256
        int k = gid >> 8, n = gid & 255;
        wsplit_one(g1w[gid], Bt1, k, n, 128);
    } else if (gid < 32768 + 131072) {       // g2: K=256, N=512
        int idx = gid - 32768;
        int k = idx >> 9, n = idx & 511;
        wsplit_one(g2w[idx], Bt2, k, n, 256);
    } else if (gid < 32768 + 131072 + 32768) { // g3 padded: K=512, N=64
        int idx = gid - 32768 - 131072;
        int k = idx >> 6, c = idx & 63;
        float w = (c < 50) ? g3w[k * 50 + c] : 0.0f;
        wsplit_one(w, Bt3, k, c, 512);
    }
}

// ---------------- fused MLP layers 1+2: x[N,3] -> h2[N,64] ------------------
// Thread per node; w1/b1/w2/b2 staged in LDS; h1 in registers.

__global__ __launch_bounds__(256) void mlp12_kernel(
        const float* __restrict__ x,
        const float* __restrict__ w1, const float* __restrict__ b1,
        const float* __restrict__ w2, const float* __restrict__ b2,
        float* __restrict__ h2, int n) {
    __shared__ float sw1[96], sb1[32], sw2[2048], sb2[64];
    int tid = threadIdx.x;
    if (tid < 96) sw1[tid] = w1[tid];
    if (tid < 32) sb1[tid] = b1[tid];
    if (tid < 64) sb2[tid] = b2[tid];
    for (int i = tid; i < 2048; i += 256) sw2[i] = w2[i];
    __syncthreads();

    int node = blockIdx.x * 256 + tid;
    if (node >= n) return;
    float x0 = x[node * 3 + 0], x1 = x[node * 3 + 1], x2 = x[node * 3 + 2];
    float h1[32];
#pragma unroll
    for (int j = 0; j < 32; j++)
        h1[j] = fmaxf(sb1[j] + x0 * sw1[j] + x1 * sw1[32 + j] + x2 * sw1[64 + j], 0.0f);

    float acc[64];
#pragma unroll
    for (int j = 0; j < 64; j++) acc[j] = sb2[j];
    for (int k = 0; k < 32; k++) {
        float hk = h1[k];
#pragma unroll
        for (int j4 = 0; j4 < 16; j4++) {
            float4 w = *(const float4*)&sw2[k * 64 + j4 * 4];
            acc[j4 * 4 + 0] = fmaf(hk, w.x, acc[j4 * 4 + 0]);
            acc[j4 * 4 + 1] = fmaf(hk, w.y, acc[j4 * 4 + 1]);
            acc[j4 * 4 + 2] = fmaf(hk, w.z, acc[j4 * 4 + 2]);
            acc[j4 * 4 + 3] = fmaf(hk, w.w, acc[j4 * 4 + 3]);
        }
    }
#pragma unroll
    for (int j4 = 0; j4 < 16; j4++) {
        float4 v;
        v.x = fmaxf(acc[j4 * 4 + 0], 0.f); v.y = fmaxf(acc[j4 * 4 + 1], 0.f);
        v.z = fmaxf(acc[j4 * 4 + 2], 0.f); v.w = fmaxf(acc[j4 * 4 + 3], 0.f);
        *(float4*)&h2[(size_t)node * 64 + j4 * 4] = v;
    }
}

// ---------------- fp32 128x128-tile GEMM (MLP layer 3: h2@w3) ---------------

template<bool BIAS, bool RELU>
__global__ __launch_bounds__(256) void gemm128_kernel(
        const float* __restrict__ A, const float* __restrict__ B,
        const float* __restrict__ bias, float* __restrict__ C,
        int M, int N, int K) {
    __shared__ float As[16][132];
    __shared__ float Bs[16][132];
    const int tid = threadIdx.x;
    const int tx = tid & 15, ty = tid >> 4;
    const int bm = blockIdx.y * 128, bn = blockIdx.x * 128;

    float acc[8][8];
#pragma unroll
    for (int i = 0; i < 8; i++)
#pragma unroll
        for (int j = 0; j < 8; j++) acc[i][j] = 0.0f;

    for (int k0 = 0; k0 < K; k0 += 16) {
#pragma unroll
        for (int i = 0; i < 2; i++) {
            int t = i * 256 + tid;
            int m = t >> 2;
            int kq = (t & 3) * 4;
            int gm = bm + m;
            float4 av = make_float4(0.f, 0.f, 0.f, 0.f);
            if (gm < M) av = *(const float4*)&A[(size_t)gm * K + k0 + kq];
            As[kq + 0][m] = av.x; As[kq + 1][m] = av.y;
            As[kq + 2][m] = av.z; As[kq + 3][m] = av.w;
        }
#pragma unroll
        for (int i = 0; i < 2; i++) {
            int t = i * 256 + tid;
            int kb = t >> 5;
            int nb = (t & 31) * 4;
            float4 bv = *(const float4*)&B[(size_t)(k0 + kb) * N + bn + nb];
            *(float4*)&Bs[kb][nb] = bv;
        }
        __syncthreads();
#pragma unroll
        for (int kk = 0; kk < 16; kk++) {
            float a[8], b[8];
            *(float4*)&a[0] = *(const float4*)&As[kk][ty * 8];
            *(float4*)&a[4] = *(const float4*)&As[kk][ty * 8 + 4];
            *(float4*)&b[0] = *(const float4*)&Bs[kk][tx * 8];
            *(float4*)&b[4] = *(const float4*)&Bs[kk][tx * 8 + 4];
#pragma unroll
            for (int i = 0; i < 8; i++)
#pragma unroll
                for (int j = 0; j < 8; j++)
                    acc[i][j] = fmaf(a[i], b[j], acc[i][j]);
        }
        __syncthreads();
    }
#pragma unroll
    for (int i = 0; i < 8; i++) {
        int gm = bm + ty * 8 + i;
        if (gm >= M) continue;
#pragma unroll
        for (int j4 = 0; j4 < 2; j4++) {
            int gn = bn + tx * 8 + j4 * 4;
            float4 v;
            v.x = acc[i][j4 * 4 + 0]; v.y = acc[i][j4 * 4 + 1];
            v.z = acc[i][j4 * 4 + 2]; v.w = acc[i][j4 * 4 + 3];
            if (BIAS) {
                v.x += bias[gn + 0]; v.y += bias[gn + 1];
                v.z += bias[gn + 2]; v.w += bias[gn + 3];
            }
            if (RELU) {
                v.x = fmaxf(v.x, 0.f); v.y = fmaxf(v.y, 0.f);
                v.z = fmaxf(v.z, 0.f); v.w = fmaxf(v.w, 0.f);
            }
            *(float4*)&C[(size_t)gm * N + gn] = v;
        }
    }
}

// ---------------- MFMA GEMM, double-bf16, global_load_lds staging -----------
// C[M,N] = (Ah+Al)[M,K] @ B[K,N], B pre-split as Bt[N][3K] = [Bh;Bl;Bh].
// MODE 0: Cf = relu(C+bias). MODE 1: relu(C+bias) split -> Ch/Cl. MODE 2: Cf=C.

template<int BN, int WGR, int WGC, int WRF, int WCF, int MODE>
__global__ __launch_bounds__(256) void gemm_mfma_kernel(
        const unsigned short* __restrict__ Ah, const unsigned short* __restrict__ Al,
        const unsigned short* __restrict__ Bt, const float* __restrict__ bias,
        float* __restrict__ Cf, unsigned short* __restrict__ Ch,
        unsigned short* __restrict__ Cl, int M, int K, int N) {
    static_assert(WGR * WRF * 16 == 128, "row cover");
    static_assert(WGC * WCF * 16 == BN, "col cover");
    __shared__ __align__(16) unsigned short As[128 * 32];
    __shared__ __align__(16) unsigned short Bs[BN * 32];

    const int tid  = threadIdx.x;
    const int lane = tid & 63;
    const int wave = tid >> 6;
    const int bm = blockIdx.y * 128;
    const int bn = blockIdx.x * BN;
    const int K2 = 2 * K, K3 = 3 * K;

    const int wr0 = (wave / WGC) * (WRF * 16);
    const int wc0 = (wave % WGC) * (WCF * 16);
    const int lr   = lane & 15;
    const int quad = lane >> 4;
    const int arow = lane >> 2;          // row within 16-row group
    const int acol = (lane & 3) * 8;     // halves within 32-half row

    floatx4 acc[WRF][WCF];
#pragma unroll
    for (int i = 0; i < WRF; i++)
#pragma unroll
        for (int j = 0; j < WCF; j++) acc[i][j] = floatx4{0.f, 0.f, 0.f, 0.f};

    for (int k0 = 0; k0 < K3; k0 += 32) {
        const unsigned short* Ap; int kk;
        if (k0 < K)       { Ap = Ah; kk = k0; }
        else if (k0 < K2) { Ap = Ah; kk = k0 - K; }
        else              { Ap = Al; kk = k0 - K2; }

#pragma unroll
        for (int i = 0; i < 2; i++) {
            int grp = wave * 2 + i;
            int gm = bm + grp * 16 + arow;
            if (gm >= M) gm = M - 1;     // clamp: garbage rows discarded at store
            gld_lds16(&As[grp * 512], Ap + (size_t)gm * K + kk + acol);
        }
#pragma unroll
        for (int i = 0; i < BN / 64; i++) {
            int grp = wave * (BN / 64) + i;
            int gr = bn + grp * 16 + arow;
            gld_lds16(&Bs[grp * 512], Bt + (size_t)gr * K3 + k0 + acol);
        }
        __syncthreads();

        short8 afr[WRF], bfr[WCF];
#pragma unroll
        for (int i = 0; i < WRF; i++)
            afr[i] = *reinterpret_cast<const short8*>(
                &As[(wr0 + i * 16 + lr) * 32 + quad * 8]);
#pragma unroll
        for (int j = 0; j < WCF; j++)
            bfr[j] = *reinterpret_cast<const short8*>(
                &Bs[(wc0 + j * 16 + lr) * 32 + quad * 8]);
#pragma unroll
        for (int i = 0; i < WRF; i++)
#pragma unroll
            for (int j = 0; j < WCF; j++)
                acc[i][j] = __builtin_amdgcn_mfma_f32_16x16x32_bf16(
                    afr[i], bfr[j], acc[i][j], 0, 0, 0);
        __syncthreads();
    }

    // epilogue: C/D layout col=lane&15, row=quad*4+reg (m89-verified)
#pragma unroll
    for (int i = 0; i < WRF; i++) {
#pragma unroll
        for (int j = 0; j < WCF; j++) {
            int gc = bn + wc0 + j * 16 + lr;
#pragma unroll
            for (int reg = 0; reg < 4; reg++) {
                int gr = bm + wr0 + i * 16 + quad * 4 + reg;
                if (gr >= M) continue;
                float v = acc[i][j][reg];
                if (MODE == 0) {
                    v = fmaxf(v + bias[gc], 0.0f);
                    Cf[(size_t)gr * N + gc] = v;
                } else if (MODE == 1) {
                    v = fmaxf(v + bias[gc], 0.0f);
                    unsigned short h = bf16h(v);
                    unsigned short l = bf16h(v - bf16f(h));
                    Ch[(size_t)gr * N + gc] = h;
                    Cl[(size_t)gr * N + gc] = l;
                } else {
                    Cf[(size_t)gr * N + gc] = v;
                }
            }
        }
    }
}

// ---------------- aggregation (R3 form): thread per (node, float4-chunk) ----
// out = AGG(hw) split into bf16 hi/lo planes (MFMA A operand).

template<int F>
__global__ void agg_split_kernel(const float* __restrict__ hw,
                                 const int* __restrict__ offsets,
                                 const int* __restrict__ ssrc,
                                 const float* __restrict__ snorm,
                                 const float* __restrict__ dinv,
                                 unsigned short* __restrict__ Ah,
                                 unsigned short* __restrict__ Al, int n) {
    constexpr int F4 = F / 4;
    int gid = blockIdx.x * blockDim.x + threadIdx.x;
    if (gid >= n * F4) return;
    int node = gid / F4;
    int c4 = (gid - node * F4) * 4;

    float4 acc = make_float4(0.f, 0.f, 0.f, 0.f);
    int beg = offsets[node], end = offsets[node + 1];
    for (int e = beg; e < end; ++e) {
        int s = ssrc[e];
        float w = snorm[e];
        float4 r = *(const float4*)&hw[(size_t)s * F + c4];
        acc.x = fmaf(r.x, w, acc.x); acc.y = fmaf(r.y, w, acc.y);
        acc.z = fmaf(r.z, w, acc.z); acc.w = fmaf(r.w, w, acc.w);
    }
    float dv = dinv[node];
    float sw = dv * dv;
    float4 r = *(const float4*)&hw[(size_t)node * F + c4];
    acc.x = fmaf(r.x, sw, acc.x); acc.y = fmaf(r.y, sw, acc.y);
    acc.z = fmaf(r.z, sw, acc.z); acc.w = fmaf(r.w, sw, acc.w);

    float vals[4] = {acc.x, acc.y, acc.z, acc.w};
    ushort4 h4, l4;
    unsigned short* hp = (unsigned short*)&h4;
    unsigned short* lp = (unsigned short*)&l4;
#pragma unroll
    for (int t = 0; t < 4; t++) {
        unsigned short h = bf16h(vals[t]);
        hp[t] = h;
        lp[t] = bf16h(vals[t] - bf16f(h));
    }
    *(ushort4*)&Ah[(size_t)node * F + c4] = h4;
    *(ushort4*)&Al[(size_t)node * F + c4] = l4;
}

// ---------------- fused final aggregation + softmax: one wave per node ------
// z[N,64] (cols 50..63 zero); out[N,50] = softmax(AGG(z)+bias).

__global__ void agg50_softmax_kernel(const float* __restrict__ z,
                                     const int* __restrict__ offsets,
                                     const int* __restrict__ ssrc,
                                     const float* __restrict__ snorm,
                                     const float* __restrict__ dinv,
                                     const float* __restrict__ bias,
                                     float* __restrict__ out, int n) {
    int node = blockIdx.x * 4 + (threadIdx.x >> 6);
    int lane = threadIdx.x & 63;
    if (node >= n) return;

    float a = 0.0f;
    int beg = offsets[node], end = offsets[node + 1];
    for (int e = beg; e < end; ++e) {
        int s = ssrc[e];
        a = fmaf(z[(size_t)s * 64 + lane], snorm[e], a);
    }
    float dv = dinv[node];
    a = fmaf(z[(size_t)node * 64 + lane], dv * dv, a);

    float v = (lane < 50) ? a + bias[lane] : -INFINITY;
    float m = v;
#pragma unroll
    for (int off = 32; off > 0; off >>= 1) m = fmaxf(m, __shfl_xor(m, off));
    float e = (lane < 50) ? expf(v - m) : 0.0f;
    float s = e;
#pragma unroll
    for (int off = 32; off > 0; off >>= 1) s += __shfl_xor(s, off);
    if (lane < 50) out[(size_t)node * 50 + lane] = e / s;
}

// ---------------------------------------------------------------------------

extern "C" void kernel_launch(void* const* d_in, const int* in_sizes, int n_in,
                              void* d_out, int out_size, void* d_ws, size_t ws_size,
                              hipStream_t stream) {
    const float* x    = (const float*)d_in[0];
    const int*   ei   = (const int*)  d_in[1];
    const float* w1   = (const float*)d_in[2];
    const float* b1   = (const float*)d_in[3];
    const float* w2   = (const float*)d_in[4];
    const float* b2   = (const float*)d_in[5];
    const float* w3   = (const float*)d_in[6];
    const float* b3   = (const float*)d_in[7];
    const float* g1w  = (const float*)d_in[8];
    const float* g1b  = (const float*)d_in[9];
    const float* g2w  = (const float*)d_in[10];
    const float* g2b  = (const float*)d_in[11];
    const float* g3w  = (const float*)d_in[12];
    const float* g3b  = (const float*)d_in[13];
    float* out = (float*)d_out;

    const int N = in_sizes[0] / 3;      // 50000
    const int E = in_sizes[1] / 2;      // 800000
    const int* src = ei;
    const int* dst = ei + E;
    const int NB = (N + 255) / 256;     // scan blocks (196)

    // ---- workspace arena with liveness-based region reuse ----
    char* ws = (char*)d_ws;
    size_t off = 0;
    auto alloc = [&](size_t bytes) -> char* {
        char* p = ws + off;
        off = (off + bytes + 255) & ~(size_t)255;
        return p;
    };
    int*   counts  = (int*)  alloc((size_t)N * 4);
    int*   offsets = (int*)  alloc((size_t)(N + 1) * 4);
    int*   cursor  = (int*)  alloc((size_t)N * 4);
    float* dinv    = (float*)alloc((size_t)N * 4);
    int*   bsum    = (int*)  alloc((size_t)256 * 4);
    int*   bsumx   = (int*)  alloc((size_t)256 * 4);
    int*   ssrc    = (int*)  alloc((size_t)E * 4);
    float* snorm   = (float*)alloc((size_t)E * 4);
    unsigned short* Bt1 = (unsigned short*)alloc((size_t)256 * 384 * 2);
    unsigned short* Bt2 = (unsigned short*)alloc((size_t)512 * 768 * 2);
    unsigned short* Bt3 = (unsigned short*)alloc((size_t)64 * 1536 * 2);
    char* R1 = alloc((size_t)N * 256 * 4);   // 51.2 MB
    char* R2 = alloc((size_t)N * 256 * 4);   // 51.2 MB
    char* R3 = alloc((size_t)N * 512 * 4);   // 102.4 MB
    (void)ws_size;

    // R1 phase 1: S128 fp32 | A128h | A128l     R1 phase 2: A256h | A256l
    float*          S128  = (float*)R1;
    unsigned short* A128h = (unsigned short*)(R1 + (size_t)N * 128 * 4);
    unsigned short* A128l = (unsigned short*)(R1 + (size_t)N * 128 * 6);
    unsigned short* A256h = (unsigned short*)R1;
    unsigned short* A256l = (unsigned short*)(R1 + (size_t)N * 256 * 2);
    // R2 phase 1: H2 [N,64] fp32    phase 2: G1 fp32 [N,256]   phase 3: z [N,64]
    float* H2   = (float*)R2;
    float* G1   = (float*)R2;
    float* zbuf = (float*)R2;
    // R3: A512h | A512l
    unsigned short* A512h = (unsigned short*)R3;
    unsigned short* A512l = (unsigned short*)(R3 + (size_t)N * 512 * 2);

    // ---- degree + CSR + weight prep ----
    hipMemsetAsync(counts, 0, (size_t)N * 4, stream);
    hist_kernel<<<(E + 255) / 256, 256, 0, stream>>>(dst, counts, E);
    scan1_kernel<<<NB, 256, 0, stream>>>(counts, bsum, N);
    scan2_kernel<<<1, 256, 0, stream>>>(bsum, bsumx, offsets, NB, N);
    scan3_kernel<<<NB, 256, 0, stream>>>(counts, bsumx, offsets, cursor, dinv, N);
    fill_kernel<<<(E + 255) / 256, 256, 0, stream>>>(src, dst, dinv, cursor, ssrc, snorm, E);
    prepw_kernel<<<(196608 + 255) / 256, 256, 0, stream>>>(g1w, g2w, g3w, Bt1, Bt2, Bt3);

    const int MB = (N + 127) / 128;     // 391 row-blocks

    // ---- MLP: x -> h2 (fused), h2 -> h3=S128 (fp32 GEMM) ----
    mlp12_kernel<<<NB * 256 / 256, 256, 0, stream>>>(x, w1, b1, w2, b2, H2, N);
    {   dim3 grid(1, MB);
        gemm128_kernel<true, true><<<grid, 256, 0, stream>>>(H2, w3, b3, S128, N, 128, 64);
    }

    // ---- GCN1: agg@128 (split out) -> MFMA GEMM 128->256 (fp32 out) ----
    agg_split_kernel<128><<<((size_t)N * 32 + 255) / 256, 256, 0, stream>>>(
        S128, offsets, ssrc, snorm, dinv, A128h, A128l, N);
    {   dim3 grid(2, MB);
        gemm_mfma_kernel<128, 2, 2, 4, 4, 0><<<grid, 256, 0, stream>>>(
            A128h, A128l, Bt1, g1b, G1, nullptr, nullptr, N, 128, 256);
    }

    // ---- GCN2: agg@256 (split out) -> MFMA GEMM 256->512 (split out) ----
    agg_split_kernel<256><<<((size_t)N * 64 + 255) / 256, 256, 0, stream>>>(
        G1, offsets, ssrc, snorm, dinv, A256h, A256l, N);
    {   dim3 grid(4, MB);
        gemm_mfma_kernel<128, 2, 2, 4, 4, 1><<<grid, 256, 0, stream>>>(
            A256h, A256l, Bt2, g2b, nullptr, A512h, A512l, N, 256, 512);
    }

    // ---- GCN3: MFMA GEMM 512->64 (fp32 out) -> fused agg@64 + softmax ----
    {   dim3 grid(1, MB);
        gemm_mfma_kernel<64, 4, 1, 2, 4, 2><<<grid, 256, 0, stream>>>(
            A512h, A512l, Bt3, nullptr, zbuf, nullptr, nullptr, N, 512, 64);
    }
    agg50_softmax_kernel<<<(N + 3) / 4, 256, 0, stream>>>(
        zbuf, offsets, ssrc, snorm, dinv, g3b, out, N);
}